// Round 15
// baseline (510.489 us; speedup 1.0000x reference)
//
#include <hip/hip_runtime.h>
#include <math.h>

// Problem constants: B=4, L=1024, D_IN=128, D_MODEL=512, N_LAYERS=2,
// N_CLASSES=3, D_INNER=1024, D_STATE=64, D_CONV=2, DT_RANK=32, BL=4096.
//
// Precision plan: all GEMM operands f16 (conversions hoisted upstream).
// Residual h: layer-1 h f16 scaled by 2^8 (exact), layer-2 h fp32 for the
// head. y scaled by 2^14 at the scan store; out_proj rescales. All scales
// exact powers of two.
//
// R15: scan BC tile transposed to [s][t] (stride 20 floats) — Bv/Cv reads
// become 4+4 ds_read_b128 per chunk instead of 32 ds_read_b32.

using half8  = __attribute__((ext_vector_type(8))) _Float16;
using half4v = __attribute__((ext_vector_type(4))) _Float16;
using f32x4  = __attribute__((ext_vector_type(4))) float;

#define Y_SCALE 16384.0f   // 2^14
#define H1_SCALE 256.0f    // 2^8

__device__ __forceinline__ float silu_f(float v) {
  return v / (1.f + __expf(-v));
}

// ---------------------------------------------------------------------------
// One-shot fp32 -> f16 conversion of all weights + x into the w16 pool.
//   exp_w 0..65536 | in_w ..2162688 | xproj_w ..2490368 | dtproj_w ..2555904
//   | out_w ..3604480 | x ..4128768
// ---------------------------------------------------------------------------
__global__ void wcvt_kernel(const float* __restrict__ exp_w,
                            const float* __restrict__ in_w,
                            const float* __restrict__ xproj_w,
                            const float* __restrict__ dtproj_w,
                            const float* __restrict__ out_w,
                            const float* __restrict__ x,
                            _Float16* __restrict__ w16)
{
  size_t gi = ((size_t)blockIdx.x * 256 + threadIdx.x) * 4;
  const float* src; size_t off;
  if      (gi < 65536)   { src = exp_w;    off = gi; }
  else if (gi < 2162688) { src = in_w;     off = gi - 65536; }
  else if (gi < 2490368) { src = xproj_w;  off = gi - 2162688; }
  else if (gi < 2555904) { src = dtproj_w; off = gi - 2490368; }
  else if (gi < 3604480) { src = out_w;    off = gi - 2555904; }
  else                   { src = x;        off = gi - 3604480; }
  float4 v = *(const float4*)(src + off);
  half4v h;
  h[0] = (_Float16)v.x; h[1] = (_Float16)v.y;
  h[2] = (_Float16)v.z; h[3] = (_Float16)v.w;
  *(half4v*)(w16 + gi) = h;
}

// ---------------------------------------------------------------------------
// f16 MFMA GEMM, 64 x BN tile. Block 256 thr = 4 waves; wave-tile 32 x (BN/2),
// MI=2 m-frags. BK=32. A and W both f16: staging is pure half8 load ->
// ds_write. Modes as R14 (0 plain / 1 in_proj fused / 2 xproj split /
// 3 dtproj transposed-softplus).
// MFMA layouts (m89/m120-verified): A-frag A[m=lane&15][k=q*8+j],
// B-frag B[k=q*8+j][n=lane&15], D: col(n)=lane&15, row(m)=q*4+r.
// ---------------------------------------------------------------------------
template<int BN, int ACT, int OF16, int MODE>
__global__ __launch_bounds__(256)
void gemm_mfma(const _Float16* __restrict__ A, int lda,
               const _Float16* __restrict__ W,
               const float* __restrict__ bias,
               void* __restrict__ Cv, int ldc,
               int N, int K, float oscale,
               void* __restrict__ Cv2)
{
  constexpr int NF = BN / 32;            // n-frags per wave
  __shared__ _Float16 As[64 * 40];       // [m][k], row stride 40 f16 (80 B)
  __shared__ _Float16 Ws[BN * 40];       // [n][k]
  __shared__ _Float16 Tz[(MODE == 1) ? 128 * 72 : 8];   // z-half transpose
  __shared__ float    Td[(MODE == 3) ? 64 * 68  : 2];   // dtproj transpose
  const int tid  = threadIdx.x;
  const int lane = tid & 63;
  const int wid  = tid >> 6;
  const int wm   = wid & 1, wn = wid >> 1;   // wave-tile: 32 m x BN/2 n
  const int m0   = blockIdx.y * 64;
  const int n0   = blockIdx.x * BN;
  const int q    = lane >> 4, l16 = lane & 15;

  // A staging: 64 rows, 4 threads/row, 8 halfs each
  const int ar  = tid >> 2;
  const int akq = (tid & 3) * 8;
  // W staging: BN=128: 2 thr/row x 16 halfs; BN=64: 4 thr/row x 8 halfs
  const int wr  = (BN == 128) ? (tid >> 1) : (tid >> 2);
  const int wkq = (BN == 128) ? ((tid & 1) * 16) : ((tid & 3) * 8);
  const int wrow = n0 + wr;
  const bool wv  = (wrow < N);

  const _Float16* Wp = W + (size_t)wrow * K;
  const size_t aoff = (size_t)(m0 + ar) * lda + akq;

  half8 zh;
  #pragma unroll
  for (int i = 0; i < 8; ++i) zh[i] = (_Float16)0.f;

  // initial loads (k0 = 0)
  half8 rah = *(const half8*)(A + aoff);
  half8 rwh0 = zh, rwh1 = zh;
  if (wv) {
    rwh0 = *(const half8*)(Wp + wkq);
    if (BN == 128) rwh1 = *(const half8*)(Wp + wkq + 8);
  }

  f32x4 acc[2][NF];
  #pragma unroll
  for (int mi = 0; mi < 2; ++mi)
    #pragma unroll
    for (int ni = 0; ni < NF; ++ni)
      acc[mi][ni] = (f32x4){0.f, 0.f, 0.f, 0.f};

  for (int k0 = 0; k0 < K; k0 += 32) {
    if (k0) __syncthreads();
    *(half8*)&As[ar * 40 + akq] = rah;
    *(half8*)&Ws[wr * 40 + wkq] = rwh0;
    if (BN == 128) *(half8*)&Ws[wr * 40 + wkq + 8] = rwh1;
    __syncthreads();

    if (k0 + 32 < K) {            // prefetch next chunk
      const int kn = k0 + 32;
      rah = *(const half8*)(A + aoff + kn);
      if (wv) {
        rwh0 = *(const half8*)(Wp + kn + wkq);
        if (BN == 128) rwh1 = *(const half8*)(Wp + kn + wkq + 8);
      }
    }

    half8 af[2], wf[NF];
    #pragma unroll
    for (int mi = 0; mi < 2; ++mi)
      af[mi] = *(const half8*)&As[(wm * 32 + mi * 16 + l16) * 40 + q * 8];
    #pragma unroll
    for (int ni = 0; ni < NF; ++ni)
      wf[ni] = *(const half8*)&Ws[(wn * (BN / 2) + ni * 16 + l16) * 40 + q * 8];
    #pragma unroll
    for (int mi = 0; mi < 2; ++mi)
      #pragma unroll
      for (int ni = 0; ni < NF; ++ni)
        acc[mi][ni] = __builtin_amdgcn_mfma_f32_16x16x32_f16(af[mi], wf[ni],
                                                             acc[mi][ni], 0, 0, 0);
  }

  float*    Cf = (float*)Cv;
  _Float16* Ch = (_Float16*)Cv;

  if (MODE == 1) {
    if (n0 < 1024) {
      // xc half: fp32 [M][1024]
      #pragma unroll
      for (int ni = 0; ni < NF; ++ni) {
        const int n = n0 + wn * (BN / 2) + ni * 16 + l16;
        #pragma unroll
        for (int mi = 0; mi < 2; ++mi) {
          const int mb = m0 + wm * 32 + mi * 16 + q * 4;
          #pragma unroll
          for (int r = 0; r < 4; ++r)
            Cf[(size_t)(mb + r) * 1024 + n] = acc[mi][ni][r] * oscale;
        }
      }
    } else {
      // z half: silu -> f16, LDS transpose, coalesced 16B row stores
      _Float16* Ch2 = (_Float16*)Cv2;
      __syncthreads();
      #pragma unroll
      for (int ni = 0; ni < NF; ++ni) {
        const int nnl = wn * (BN / 2) + ni * 16 + l16;   // 0..127 local
        #pragma unroll
        for (int mi = 0; mi < 2; ++mi) {
          const int mbl = wm * 32 + mi * 16 + q * 4;     // 0..63 local
          half4v h4;
          #pragma unroll
          for (int r = 0; r < 4; ++r)
            h4[r] = (_Float16)silu_f(acc[mi][ni][r] * oscale);
          *(half4v*)&Tz[nnl * 72 + mbl] = h4;
        }
      }
      __syncthreads();
      const int sr = tid >> 3;          // 0..31
      const int sc = (tid & 7) * 8;     // halfs 0..56
      #pragma unroll
      for (int rd = 0; rd < 4; ++rd) {
        const int row = rd * 32 + sr;
        half8 v = *(const half8*)&Tz[row * 72 + sc];
        *(half8*)&Ch2[(size_t)(n0 - 1024 + row) * 4096 + m0 + sc] = v;
      }
    }
    return;
  }

  if (MODE == 2) {
    // xproj: n<32 -> dtr16 f16 [M][32]; 32<=n<160 -> dbc fp32 [M][160]
    _Float16* dtr = (_Float16*)Cv2;
    #pragma unroll
    for (int ni = 0; ni < NF; ++ni) {
      const int n = n0 + wn * (BN / 2) + ni * 16 + l16;
      #pragma unroll
      for (int mi = 0; mi < 2; ++mi) {
        const int mb = m0 + wm * 32 + mi * 16 + q * 4;
        if (n < 32) {
          #pragma unroll
          for (int r = 0; r < 4; ++r)
            dtr[(size_t)(mb + r) * 32 + n] = (_Float16)acc[mi][ni][r];
        } else if (n < 160) {
          #pragma unroll
          for (int r = 0; r < 4; ++r)
            Cf[(size_t)(mb + r) * 160 + n] = acc[mi][ni][r];
        }
      }
    }
    return;
  }

  if (MODE == 3) {
    // dtproj: softplus(acc*oscale + bias) -> fp32 [N][4096] via LDS transpose
    __syncthreads();
    #pragma unroll
    for (int ni = 0; ni < NF; ++ni) {
      const int nnl = wn * (BN / 2) + ni * 16 + l16;     // 0..63 local
      const float bv = (bias != nullptr) ? bias[n0 + nnl] : 0.f;
      #pragma unroll
      for (int mi = 0; mi < 2; ++mi) {
        const int mbl = wm * 32 + mi * 16 + q * 4;       // 0..63 local
        float o[4];
        #pragma unroll
        for (int r = 0; r < 4; ++r) {
          float v = acc[mi][ni][r] * oscale + bv;
          o[r] = (v > 20.f) ? v : log1pf(__expf(v));     // softplus
        }
        *(float4*)&Td[nnl * 68 + mbl] = make_float4(o[0], o[1], o[2], o[3]);
      }
    }
    __syncthreads();
    const int sr = tid >> 4;            // 0..15
    const int sc = (tid & 15) * 4;      // floats 0..60
    #pragma unroll
    for (int rd = 0; rd < 4; ++rd) {
      const int row = rd * 16 + sr;
      float4 v = *(const float4*)&Td[row * 68 + sc];
      *(float4*)&Cf[(size_t)(n0 + row) * 4096 + m0 + sc] = v;
    }
    return;
  }

  // MODE 0 epilogue
  #pragma unroll
  for (int ni = 0; ni < NF; ++ni) {
    const int n = n0 + wn * (BN / 2) + ni * 16 + l16;
    if (n < N) {
      const float bv = (bias != nullptr) ? bias[n] : 0.f;
      #pragma unroll
      for (int mi = 0; mi < 2; ++mi) {
        const int mb = m0 + wm * 32 + mi * 16 + q * 4;
        #pragma unroll
        for (int r = 0; r < 4; ++r) {
          float v = acc[mi][ni][r] * oscale + bv;
          if (ACT == 1) v = (v > 20.f) ? v : log1pf(__expf(v));
          if (ACT == 2) v = silu_f(v);
          size_t off = (size_t)(mb + r) * ldc + n;
          if (OF16) Ch[off] = (_Float16)v;
          else      Cf[off] = v;
        }
      }
    }
  }
}

// ---------------------------------------------------------------------------
// Depthwise causal conv (D_CONV=2) + silu, 64x64 LDS transpose.
// in : xcp [4096 bl][1024 d] fp32
// out: xcT [1024 d][4096 bl] fp32 (scan input)  +  xcf [4096 bl][1024 d] f16
// ---------------------------------------------------------------------------
__global__ void conv_t_kernel(const float* __restrict__ xcp,
                              const float* __restrict__ cw,   // [1024][2]
                              const float* __restrict__ cb,   // [1024]
                              float* __restrict__ xcT,
                              _Float16* __restrict__ xcf)
{
  __shared__ float tile[64][65];
  const int blk = blockIdx.x;            // b*256 + tt*16 + dd
  const int b  = blk >> 8;
  const int tt = (blk >> 4) & 15;
  const int dd = blk & 15;
  const int t0 = tt * 64, d0 = dd * 64;
  const int tid = threadIdx.x;

  #pragma unroll
  for (int i = 0; i < 16; ++i) {
    int idx = i * 256 + tid;
    int t = idx >> 6, d = idx & 63;
    int gt = t0 + t;
    size_t rcur = ((size_t)(b * 1024 + gt) << 10) + d0 + d;
    float cur  = xcp[rcur];
    float prev = (gt > 0) ? xcp[rcur - 1024] : 0.f;
    float v = fmaf(prev, cw[(d0+d)*2], fmaf(cur, cw[(d0+d)*2 + 1], cb[d0+d]));
    float sv = silu_f(v);
    tile[t][d] = sv;
    xcf[rcur] = (_Float16)sv;
  }
  __syncthreads();
  #pragma unroll
  for (int i = 0; i < 16; ++i) {
    int idx = i * 256 + tid;
    int d = idx >> 6, t = idx & 63;
    xcT[((size_t)(d0 + d) << 12) + b * 1024 + t0 + t] = tile[t][d];
  }
}

// ---------------------------------------------------------------------------
// Selective scan, time-major. One wave per (b,d), lane = s (D_STATE=64).
// R9 core + R12 XCD swizzle + direct f16 y store.
// R15: BC tile transposed to [s][t] (row stride 20 floats, 80B — b128-
// aligned, bank-spread): each lane reads its own contiguous row, so Bv/Cv
// = 4+4 ds_read_b128 per chunk instead of 32 ds_read_b32. Staging writes
// become 4 ds_write_b32 per tensor per thread. Bit-identical arithmetic.
// ---------------------------------------------------------------------------
__global__ __launch_bounds__(256, 4)
void scan_kernel(const float* __restrict__ dtT,     // [1024][4096]
                 const float* __restrict__ xcT,     // [1024][4096]
                 const _Float16* __restrict__ zsT,  // [1024][4096], silu(z), f16
                 const float* __restrict__ dbc,     // [B][1024][160]; B@+32, C@+96
                 const float* __restrict__ A_log,   // [1024][64]
                 const float* __restrict__ Dp,      // [1024]
                 _Float16* __restrict__ y16)        // [4096 bl][1024 d], y*2^14
{
  __shared__ float P[4][16][68];       // per-wave reduction tile
  __shared__ float BCt[2][2][64][20];  // [buf][B/C][s][t], stride 20 pad
  const int tid  = threadIdx.x;
  const int lane = tid & 63;
  const int wrp  = tid >> 6;
  const int rb   = blockIdx.x;
  const int bswz = ((rb & 7) << 7) | (rb >> 3);          // XCD swizzle
  const int wid  = __builtin_amdgcn_readfirstlane(bswz * 4 + wrp);
  const int b = wid >> 10;             // block-uniform
  const int d = wid & 1023;
  float (*Pw)[68] = P[wrp];

  const float a   = -__expf(A_log[d*64 + lane]);
  const float dpv = Dp[d];
  const size_t row = ((size_t)d << 12) + b * 1024;
  const float*    dtp = dtT + row;
  const float*    xp  = xcT + row;
  const _Float16* zsp = zsT + row;
  _Float16*       yp  = y16 + ((size_t)b << 20) + d;     // + t*1024

  // cooperative staging coords: thread -> (t in chunk, s-quad)
  const int ct = tid >> 4;             // 0..15  (t)
  const int cs = (tid & 15) * 4;       // 0..60  (s)
  const float* bcbase = dbc + (size_t)b * 163840 + (size_t)ct * 160 + cs;

  const int tt_r = lane >> 2;
  const int c0   = (lane & 3) << 4;

  // preload chunk 0 into buf 0 (transposed)
  {
    float4 b0 = *(const float4*)(bcbase + 32);
    float4 c0q = *(const float4*)(bcbase + 96);
    BCt[0][0][cs+0][ct] = b0.x;  BCt[0][0][cs+1][ct] = b0.y;
    BCt[0][0][cs+2][ct] = b0.z;  BCt[0][0][cs+3][ct] = b0.w;
    BCt[0][1][cs+0][ct] = c0q.x; BCt[0][1][cs+1][ct] = c0q.y;
    BCt[0][1][cs+2][ct] = c0q.z; BCt[0][1][cs+3][ct] = c0q.w;
  }
  __syncthreads();

  float h = 0.f;
  for (int t0 = 0; t0 < 1024; t0 += 16) {
    const int p = (t0 >> 4) & 1;
    // ---- issue next chunk's global loads first ----
    const int tn = (t0 + 16 < 1024) ? (t0 + 16) : t0;
    float4 nb = *(const float4*)(bcbase + (size_t)tn * 160 + 32);
    float4 nc = *(const float4*)(bcbase + (size_t)tn * 160 + 96);

    // ---- per-wave loads for current chunk ----
    float4 dq[4], xq[4];
    #pragma unroll
    for (int i = 0; i < 4; ++i) {
      dq[i] = *(const float4*)(dtp + t0 + i*4);
      xq[i] = *(const float4*)(xp  + t0 + i*4);
    }
    float zs  = (float)zsp[t0 + tt_r] * Y_SCALE;   // exact 2^14 fold
    float xvl = xp[t0 + tt_r];

    // ---- Bv/Cv: own contiguous row, 4+4 ds_read_b128 ----
    float4 bv4[4], cv4[4];
    #pragma unroll
    for (int i = 0; i < 4; ++i) {
      bv4[i] = *(const float4*)&BCt[p][0][lane][i*4];
      cv4[i] = *(const float4*)&BCt[p][1][lane][i*4];
    }
    const float* Bv  = reinterpret_cast<const float*>(bv4);
    const float* Cv  = reinterpret_cast<const float*>(cv4);
    const float* dtv = reinterpret_cast<const float*>(dq);
    const float* xv  = reinterpret_cast<const float*>(xq);

    // ---- parallel phase: everything h-independent ----
    float dA[16], ub[16];
    #pragma unroll
    for (int tt = 0; tt < 16; ++tt) {
      dA[tt] = __expf(dtv[tt] * a);
      ub[tt] = dtv[tt] * xv[tt] * Bv[tt];
    }
    // ---- serial recurrence: fma -> mul -> ds_write per t ----
    #pragma unroll
    for (int tt = 0; tt < 16; ++tt) {
      h = fmaf(h, dA[tt], ub[tt]);
      Pw[tt][lane] = h * Cv[tt];
    }

    // ---- batched reduction: lane L sums 16 states of timestep L>>2 ----
    float4 s0 = *(const float4*)&Pw[tt_r][c0];
    float4 s1 = *(const float4*)&Pw[tt_r][c0 + 4];
    float4 s2 = *(const float4*)&Pw[tt_r][c0 + 8];
    float4 s3 = *(const float4*)&Pw[tt_r][c0 + 12];
    float r = ((s0.x + s0.y) + (s0.z + s0.w))
            + ((s1.x + s1.y) + (s1.z + s1.w))
            + ((s2.x + s2.y) + (s2.z + s2.w))
            + ((s3.x + s3.y) + (s3.z + s3.w));
    r += __shfl_xor(r, 1, 64);
    r += __shfl_xor(r, 2, 64);
    if ((lane & 3) == 0)
      yp[(size_t)(t0 + tt_r) << 10] = (_Float16)(fmaf(xvl, dpv, r) * zs);

    // ---- stage next BC buffer (transposed), then sync ----
    const int np = 1 - p;
    BCt[np][0][cs+0][ct] = nb.x;  BCt[np][0][cs+1][ct] = nb.y;
    BCt[np][0][cs+2][ct] = nb.z;  BCt[np][0][cs+3][ct] = nb.w;
    BCt[np][1][cs+0][ct] = nc.x;  BCt[np][1][cs+1][ct] = nc.y;
    BCt[np][1][cs+2][ct] = nc.z;  BCt[np][1][cs+3][ct] = nc.w;
    __syncthreads();
  }
}

// out[b,c] = h[b,L-1,:] . fc_w[c,:] + fc_b[c]; h is fp32 [4096][512]
__global__ void head_kernel(const float* __restrict__ h,
                            const float* __restrict__ fc_w,
                            const float* __restrict__ fc_b,
                            float* __restrict__ out)
{
  int bc = blockIdx.x;            // 0..11
  int b = bc / 3, c = bc % 3;
  int lane = threadIdx.x;
  const float* hr = h + (size_t)(b*1024 + 1023) * 512;
  const float* wr = fc_w + c*512;
  float s = 0.f;
  #pragma unroll
  for (int i = 0; i < 8; ++i) s = fmaf(hr[lane + i*64], wr[lane + i*64], s);
  #pragma unroll
  for (int o = 32; o > 0; o >>= 1) s += __shfl_xor(s, o, 64);
  if (lane == 0) out[b*3 + c] = s + fc_b[c];
}

extern "C" void kernel_launch(void* const* d_in, const int* in_sizes, int n_in,
                              void* d_out, int out_size, void* d_ws, size_t ws_size,
                              hipStream_t stream)
{
  const float* x        = (const float*)d_in[0];
  const float* exp_w    = (const float*)d_in[1];
  const float* exp_b    = (const float*)d_in[2];
  const float* in_w     = (const float*)d_in[3];
  const float* conv_w   = (const float*)d_in[4];
  const float* conv_b   = (const float*)d_in[5];
  const float* xproj_w  = (const float*)d_in[6];
  const float* dtproj_w = (const float*)d_in[7];
  const float* dtproj_b = (const float*)d_in[8];
  const float* A_log    = (const float*)d_in[9];
  const float* Dp       = (const float*)d_in[10];
  const float* out_w    = (const float*)d_in[11];
  const float* fc_w     = (const float*)d_in[12];
  const float* fc_b     = (const float*)d_in[13];
  float* out = (float*)d_out;

  // Workspace layout (byte offsets), 72 MB total.
  // 4..20 MB region sequentially reused: xcpre -> dtT -> hf32 (l1 out).
  char* ws = (char*)d_ws;
  _Float16* hf16  = (_Float16*)(ws);                          //  4 MB [4096][512] f16
  float*    xcpre = (float*)   (ws + ((size_t)4  << 20));     // 16 MB [4096][1024]
  float*    dtT   = (float*)   (ws + ((size_t)4  << 20));     // 16 MB [1024][4096] (reuse)
  float*    hf32  = (float*)   (ws + ((size_t)4  << 20));     //  8 MB [4096][512] (reuse, l1)
  float*    xcT   = (float*)   (ws + ((size_t)20 << 20));     // 16 MB [1024][4096]
  _Float16* zsT   = (_Float16*)(ws + ((size_t)36 << 20));     //  8 MB [1024][4096]
  float*    dbc   = (float*)   (ws + ((size_t)44 << 20));     //  2.6 MB [4096][160]
  _Float16* dtr16 = (_Float16*)(ws + ((size_t)47 << 20));     //  0.25 MB [4096][32]
  _Float16* xc16  = (_Float16*)(ws + ((size_t)48 << 20));     //  8 MB [4096][1024]
  _Float16* y16   = (_Float16*)(ws + ((size_t)56 << 20));     //  8 MB [4096][1024]
  _Float16* w16   = (_Float16*)(ws + ((size_t)64 << 20));     //  7.9 MB f16 pool

  _Float16* exp16 = w16;                 // [512][128]
  _Float16* in16  = w16 + 65536;         // [2][2048][512]
  _Float16* xp16  = w16 + 2162688;       // [2][160][1024]
  _Float16* dt16  = w16 + 2490368;       // [2][1024][32]
  _Float16* out16 = w16 + 2555904;       // [2][512][1024]
  _Float16* x16   = w16 + 3604480;       // [4096][128]

  dim3 blk(256);

  // one-shot f16 conversion of all weights + x (4128768 elems, 4032 blocks)
  wcvt_kernel<<<4032, blk, 0, stream>>>(exp_w, in_w, xproj_w, dtproj_w, out_w,
                                        x, w16);

  // expand: hf16 = f16(x @ exp_w^T + exp_b)   [4096,512] K=128. 512 blocks.
  gemm_mfma<64,0,1,0><<<dim3(8,64), blk, 0, stream>>>(x16, 128, exp16, exp_b,
                                                      hf16, 512, 512, 128, 1.f,
                                                      nullptr);

  for (int l = 0; l < 2; ++l) {
    const float is = l ? (1.f / H1_SCALE) : 1.f;     // undo h1 scaling (exact)
    // fused in_proj: xcpre fp32 + zsT f16 (LDS-transposed). N=2048 K=512.
    gemm_mfma<128,0,0,1><<<dim3(16,64), blk, 0, stream>>>(hf16, 512,
                                                          in16 + (size_t)l*1048576,
                                                          nullptr, xcpre, 1024,
                                                          2048, 512, is, zsT);
    // conv + silu -> xcT (fp32, scan) + xc16 (f16, xproj A)
    conv_t_kernel<<<1024, blk, 0, stream>>>(xcpre, conv_w + l*2048, conv_b + l*1024,
                                            xcT, xc16);
    // xproj (MODE 2): dtr16 f16 [4096][32] + dbc fp32 [4096][160]. K=1024.
    gemm_mfma<64,0,0,2><<<dim3(3,64), blk, 0, stream>>>(xc16, 1024,
                                                        xp16 + (size_t)l*163840,
                                                        nullptr, dbc, 160,
                                                        160, 1024, 1.f, dtr16);
    // dtproj (MODE 3): dtT [1024][4096] softplus, LDS-transposed stores. K=32.
    gemm_mfma<64,0,0,3><<<dim3(16,64), blk, 0, stream>>>(dtr16, 32,
                                                         dt16 + (size_t)l*32768,
                                                         dtproj_b + l*1024,
                                                         dtT, 4096, 1024, 32, 1.f,
                                                         nullptr);
    // selective scan; y16 = f16((scan + x*Dp)*silu(z) * 2^14) [bl][d]
    scan_kernel<<<1024, blk, 0, stream>>>(dtT, xcT, zsT, dbc,
                                          A_log + (size_t)l*65536, Dp + l*1024, y16);
    // out_proj: l0 -> hf16 = f16(h1 * 2^8); l1 -> hf32 fp32 for the head.
    if (l == 0)
      gemm_mfma<64,0,1,0><<<dim3(8,64), blk, 0, stream>>>(y16, 1024,
                                                          out16, nullptr,
                                                          hf16, 512, 512, 1024,
                                                          H1_SCALE / Y_SCALE,
                                                          nullptr);
    else
      gemm_mfma<64,0,0,0><<<dim3(8,64), blk, 0, stream>>>(y16, 1024,
                                                          out16 + 524288, nullptr,
                                                          hf32, 512, 512, 1024,
                                                          1.f / Y_SCALE, nullptr);
  }

  head_kernel<<<12, 64, 0, stream>>>(hf32, fc_w, fc_b, out);
}

// Round 16
// 461.998 us; speedup vs baseline: 1.1050x; 1.1050x over previous
//
#include <hip/hip_runtime.h>
#include <math.h>

// Problem constants: B=4, L=1024, D_IN=128, D_MODEL=512, N_LAYERS=2,
// N_CLASSES=3, D_INNER=1024, D_STATE=64, D_CONV=2, DT_RANK=32, BL=4096.
//
// Precision plan: all GEMM operands f16 (conversions hoisted upstream).
// Residual h: layer-1 h f16 scaled by 2^8 (exact), layer-2 h fp32 for the
// head. y scaled by 2^14 at the scan store; out_proj rescales. All scales
// exact powers of two.
//
// R16: scan reverted to the R12/R14-proven BC[buf][2][16][64] layout.
// R15's [s][t] transposed tile with stride-20 rows caused 8-way bank
// conflicts (2.98e7 SQ_LDS_BANK_CONFLICT): ds_read_b128 forces row stride
// 4k floats, and gcd(4k,32)>=4 makes >=8-way conflicts inherent when 64
// lanes read 64 distinct rows. Lane-indexed b32 reads ([t][lane]) are the
// conflict-free layout for this access pattern.

using half8  = __attribute__((ext_vector_type(8))) _Float16;
using half4v = __attribute__((ext_vector_type(4))) _Float16;
using f32x4  = __attribute__((ext_vector_type(4))) float;

#define Y_SCALE 16384.0f   // 2^14
#define H1_SCALE 256.0f    // 2^8

__device__ __forceinline__ float silu_f(float v) {
  return v / (1.f + __expf(-v));
}

// ---------------------------------------------------------------------------
// One-shot fp32 -> f16 conversion of all weights + x into the w16 pool.
//   exp_w 0..65536 | in_w ..2162688 | xproj_w ..2490368 | dtproj_w ..2555904
//   | out_w ..3604480 | x ..4128768
// ---------------------------------------------------------------------------
__global__ void wcvt_kernel(const float* __restrict__ exp_w,
                            const float* __restrict__ in_w,
                            const float* __restrict__ xproj_w,
                            const float* __restrict__ dtproj_w,
                            const float* __restrict__ out_w,
                            const float* __restrict__ x,
                            _Float16* __restrict__ w16)
{
  size_t gi = ((size_t)blockIdx.x * 256 + threadIdx.x) * 4;
  const float* src; size_t off;
  if      (gi < 65536)   { src = exp_w;    off = gi; }
  else if (gi < 2162688) { src = in_w;     off = gi - 65536; }
  else if (gi < 2490368) { src = xproj_w;  off = gi - 2162688; }
  else if (gi < 2555904) { src = dtproj_w; off = gi - 2490368; }
  else if (gi < 3604480) { src = out_w;    off = gi - 2555904; }
  else                   { src = x;        off = gi - 3604480; }
  float4 v = *(const float4*)(src + off);
  half4v h;
  h[0] = (_Float16)v.x; h[1] = (_Float16)v.y;
  h[2] = (_Float16)v.z; h[3] = (_Float16)v.w;
  *(half4v*)(w16 + gi) = h;
}

// ---------------------------------------------------------------------------
// f16 MFMA GEMM, 64 x BN tile. Block 256 thr = 4 waves; wave-tile 32 x (BN/2),
// MI=2 m-frags. BK=32. A and W both f16: staging is pure half8 load ->
// ds_write. Modes: 0 plain / 1 in_proj fused / 2 xproj split / 3 dtproj
// transposed-softplus.
// MFMA layouts (m89/m120-verified): A-frag A[m=lane&15][k=q*8+j],
// B-frag B[k=q*8+j][n=lane&15], D: col(n)=lane&15, row(m)=q*4+r.
// ---------------------------------------------------------------------------
template<int BN, int ACT, int OF16, int MODE>
__global__ __launch_bounds__(256)
void gemm_mfma(const _Float16* __restrict__ A, int lda,
               const _Float16* __restrict__ W,
               const float* __restrict__ bias,
               void* __restrict__ Cv, int ldc,
               int N, int K, float oscale,
               void* __restrict__ Cv2)
{
  constexpr int NF = BN / 32;            // n-frags per wave
  __shared__ _Float16 As[64 * 40];       // [m][k], row stride 40 f16 (80 B)
  __shared__ _Float16 Ws[BN * 40];       // [n][k]
  __shared__ _Float16 Tz[(MODE == 1) ? 128 * 72 : 8];   // z-half transpose
  __shared__ float    Td[(MODE == 3) ? 64 * 68  : 2];   // dtproj transpose
  const int tid  = threadIdx.x;
  const int lane = tid & 63;
  const int wid  = tid >> 6;
  const int wm   = wid & 1, wn = wid >> 1;   // wave-tile: 32 m x BN/2 n
  const int m0   = blockIdx.y * 64;
  const int n0   = blockIdx.x * BN;
  const int q    = lane >> 4, l16 = lane & 15;

  // A staging: 64 rows, 4 threads/row, 8 halfs each
  const int ar  = tid >> 2;
  const int akq = (tid & 3) * 8;
  // W staging: BN=128: 2 thr/row x 16 halfs; BN=64: 4 thr/row x 8 halfs
  const int wr  = (BN == 128) ? (tid >> 1) : (tid >> 2);
  const int wkq = (BN == 128) ? ((tid & 1) * 16) : ((tid & 3) * 8);
  const int wrow = n0 + wr;
  const bool wv  = (wrow < N);

  const _Float16* Wp = W + (size_t)wrow * K;
  const size_t aoff = (size_t)(m0 + ar) * lda + akq;

  half8 zh;
  #pragma unroll
  for (int i = 0; i < 8; ++i) zh[i] = (_Float16)0.f;

  // initial loads (k0 = 0)
  half8 rah = *(const half8*)(A + aoff);
  half8 rwh0 = zh, rwh1 = zh;
  if (wv) {
    rwh0 = *(const half8*)(Wp + wkq);
    if (BN == 128) rwh1 = *(const half8*)(Wp + wkq + 8);
  }

  f32x4 acc[2][NF];
  #pragma unroll
  for (int mi = 0; mi < 2; ++mi)
    #pragma unroll
    for (int ni = 0; ni < NF; ++ni)
      acc[mi][ni] = (f32x4){0.f, 0.f, 0.f, 0.f};

  for (int k0 = 0; k0 < K; k0 += 32) {
    if (k0) __syncthreads();
    *(half8*)&As[ar * 40 + akq] = rah;
    *(half8*)&Ws[wr * 40 + wkq] = rwh0;
    if (BN == 128) *(half8*)&Ws[wr * 40 + wkq + 8] = rwh1;
    __syncthreads();

    if (k0 + 32 < K) {            // prefetch next chunk
      const int kn = k0 + 32;
      rah = *(const half8*)(A + aoff + kn);
      if (wv) {
        rwh0 = *(const half8*)(Wp + kn + wkq);
        if (BN == 128) rwh1 = *(const half8*)(Wp + kn + wkq + 8);
      }
    }

    half8 af[2], wf[NF];
    #pragma unroll
    for (int mi = 0; mi < 2; ++mi)
      af[mi] = *(const half8*)&As[(wm * 32 + mi * 16 + l16) * 40 + q * 8];
    #pragma unroll
    for (int ni = 0; ni < NF; ++ni)
      wf[ni] = *(const half8*)&Ws[(wn * (BN / 2) + ni * 16 + l16) * 40 + q * 8];
    #pragma unroll
    for (int mi = 0; mi < 2; ++mi)
      #pragma unroll
      for (int ni = 0; ni < NF; ++ni)
        acc[mi][ni] = __builtin_amdgcn_mfma_f32_16x16x32_f16(af[mi], wf[ni],
                                                             acc[mi][ni], 0, 0, 0);
  }

  float*    Cf = (float*)Cv;
  _Float16* Ch = (_Float16*)Cv;

  if (MODE == 1) {
    if (n0 < 1024) {
      // xc half: fp32 [M][1024]
      #pragma unroll
      for (int ni = 0; ni < NF; ++ni) {
        const int n = n0 + wn * (BN / 2) + ni * 16 + l16;
        #pragma unroll
        for (int mi = 0; mi < 2; ++mi) {
          const int mb = m0 + wm * 32 + mi * 16 + q * 4;
          #pragma unroll
          for (int r = 0; r < 4; ++r)
            Cf[(size_t)(mb + r) * 1024 + n] = acc[mi][ni][r] * oscale;
        }
      }
    } else {
      // z half: silu -> f16, LDS transpose, coalesced 16B row stores
      _Float16* Ch2 = (_Float16*)Cv2;
      __syncthreads();
      #pragma unroll
      for (int ni = 0; ni < NF; ++ni) {
        const int nnl = wn * (BN / 2) + ni * 16 + l16;   // 0..127 local
        #pragma unroll
        for (int mi = 0; mi < 2; ++mi) {
          const int mbl = wm * 32 + mi * 16 + q * 4;     // 0..63 local
          half4v h4;
          #pragma unroll
          for (int r = 0; r < 4; ++r)
            h4[r] = (_Float16)silu_f(acc[mi][ni][r] * oscale);
          *(half4v*)&Tz[nnl * 72 + mbl] = h4;
        }
      }
      __syncthreads();
      const int sr = tid >> 3;          // 0..31
      const int sc = (tid & 7) * 8;     // halfs 0..56
      #pragma unroll
      for (int rd = 0; rd < 4; ++rd) {
        const int row = rd * 32 + sr;
        half8 v = *(const half8*)&Tz[row * 72 + sc];
        *(half8*)&Ch2[(size_t)(n0 - 1024 + row) * 4096 + m0 + sc] = v;
      }
    }
    return;
  }

  if (MODE == 2) {
    // xproj: n<32 -> dtr16 f16 [M][32]; 32<=n<160 -> dbc fp32 [M][160]
    _Float16* dtr = (_Float16*)Cv2;
    #pragma unroll
    for (int ni = 0; ni < NF; ++ni) {
      const int n = n0 + wn * (BN / 2) + ni * 16 + l16;
      #pragma unroll
      for (int mi = 0; mi < 2; ++mi) {
        const int mb = m0 + wm * 32 + mi * 16 + q * 4;
        if (n < 32) {
          #pragma unroll
          for (int r = 0; r < 4; ++r)
            dtr[(size_t)(mb + r) * 32 + n] = (_Float16)acc[mi][ni][r];
        } else if (n < 160) {
          #pragma unroll
          for (int r = 0; r < 4; ++r)
            Cf[(size_t)(mb + r) * 160 + n] = acc[mi][ni][r];
        }
      }
    }
    return;
  }

  if (MODE == 3) {
    // dtproj: softplus(acc*oscale + bias) -> fp32 [N][4096] via LDS transpose
    __syncthreads();
    #pragma unroll
    for (int ni = 0; ni < NF; ++ni) {
      const int nnl = wn * (BN / 2) + ni * 16 + l16;     // 0..63 local
      const float bv = (bias != nullptr) ? bias[n0 + nnl] : 0.f;
      #pragma unroll
      for (int mi = 0; mi < 2; ++mi) {
        const int mbl = wm * 32 + mi * 16 + q * 4;       // 0..63 local
        float o[4];
        #pragma unroll
        for (int r = 0; r < 4; ++r) {
          float v = acc[mi][ni][r] * oscale + bv;
          o[r] = (v > 20.f) ? v : log1pf(__expf(v));     // softplus
        }
        *(float4*)&Td[nnl * 68 + mbl] = make_float4(o[0], o[1], o[2], o[3]);
      }
    }
    __syncthreads();
    const int sr = tid >> 4;            // 0..15
    const int sc = (tid & 15) * 4;      // floats 0..60
    #pragma unroll
    for (int rd = 0; rd < 4; ++rd) {
      const int row = rd * 16 + sr;
      float4 v = *(const float4*)&Td[row * 68 + sc];
      *(float4*)&Cf[(size_t)(n0 + row) * 4096 + m0 + sc] = v;
    }
    return;
  }

  // MODE 0 epilogue
  #pragma unroll
  for (int ni = 0; ni < NF; ++ni) {
    const int n = n0 + wn * (BN / 2) + ni * 16 + l16;
    if (n < N) {
      const float bv = (bias != nullptr) ? bias[n] : 0.f;
      #pragma unroll
      for (int mi = 0; mi < 2; ++mi) {
        const int mb = m0 + wm * 32 + mi * 16 + q * 4;
        #pragma unroll
        for (int r = 0; r < 4; ++r) {
          float v = acc[mi][ni][r] * oscale + bv;
          if (ACT == 1) v = (v > 20.f) ? v : log1pf(__expf(v));
          if (ACT == 2) v = silu_f(v);
          size_t off = (size_t)(mb + r) * ldc + n;
          if (OF16) Ch[off] = (_Float16)v;
          else      Cf[off] = v;
        }
      }
    }
  }
}

// ---------------------------------------------------------------------------
// Depthwise causal conv (D_CONV=2) + silu, 64x64 LDS transpose.
// in : xcp [4096 bl][1024 d] fp32
// out: xcT [1024 d][4096 bl] fp32 (scan input)  +  xcf [4096 bl][1024 d] f16
// ---------------------------------------------------------------------------
__global__ void conv_t_kernel(const float* __restrict__ xcp,
                              const float* __restrict__ cw,   // [1024][2]
                              const float* __restrict__ cb,   // [1024]
                              float* __restrict__ xcT,
                              _Float16* __restrict__ xcf)
{
  __shared__ float tile[64][65];
  const int blk = blockIdx.x;            // b*256 + tt*16 + dd
  const int b  = blk >> 8;
  const int tt = (blk >> 4) & 15;
  const int dd = blk & 15;
  const int t0 = tt * 64, d0 = dd * 64;
  const int tid = threadIdx.x;

  #pragma unroll
  for (int i = 0; i < 16; ++i) {
    int idx = i * 256 + tid;
    int t = idx >> 6, d = idx & 63;
    int gt = t0 + t;
    size_t rcur = ((size_t)(b * 1024 + gt) << 10) + d0 + d;
    float cur  = xcp[rcur];
    float prev = (gt > 0) ? xcp[rcur - 1024] : 0.f;
    float v = fmaf(prev, cw[(d0+d)*2], fmaf(cur, cw[(d0+d)*2 + 1], cb[d0+d]));
    float sv = silu_f(v);
    tile[t][d] = sv;
    xcf[rcur] = (_Float16)sv;
  }
  __syncthreads();
  #pragma unroll
  for (int i = 0; i < 16; ++i) {
    int idx = i * 256 + tid;
    int d = idx >> 6, t = idx & 63;
    xcT[((size_t)(d0 + d) << 12) + b * 1024 + t0 + t] = tile[t][d];
  }
}

// ---------------------------------------------------------------------------
// Selective scan, time-major. One wave per (b,d), lane = s (D_STATE=64).
// R12/R14-proven core: B/C block-shared in LDS BC[buf][2][16][64]
// (double-buffered, lane-indexed b32 reads — conflict-free), one barrier
// per chunk, wave-private P reduction tile, XCD swizzle, direct f16 y
// store (x 2^14 exact).
// ---------------------------------------------------------------------------
__global__ __launch_bounds__(256, 4)
void scan_kernel(const float* __restrict__ dtT,     // [1024][4096]
                 const float* __restrict__ xcT,     // [1024][4096]
                 const _Float16* __restrict__ zsT,  // [1024][4096], silu(z), f16
                 const float* __restrict__ dbc,     // [B][1024][160]; B@+32, C@+96
                 const float* __restrict__ A_log,   // [1024][64]
                 const float* __restrict__ Dp,      // [1024]
                 _Float16* __restrict__ y16)        // [4096 bl][1024 d], y*2^14
{
  __shared__ float P[4][16][68];       // per-wave reduction tile
  __shared__ float BC[2][2][16][64];   // [buf][B/C][t][s], block-shared
  const int tid  = threadIdx.x;
  const int lane = tid & 63;
  const int wrp  = tid >> 6;
  const int rb   = blockIdx.x;
  const int bswz = ((rb & 7) << 7) | (rb >> 3);          // XCD swizzle
  const int wid  = __builtin_amdgcn_readfirstlane(bswz * 4 + wrp);
  const int b = wid >> 10;             // block-uniform
  const int d = wid & 1023;
  float (*Pw)[68] = P[wrp];

  const float a   = -__expf(A_log[d*64 + lane]);
  const float dpv = Dp[d];
  const size_t row = ((size_t)d << 12) + b * 1024;
  const float*    dtp = dtT + row;
  const float*    xp  = xcT + row;
  const _Float16* zsp = zsT + row;
  _Float16*       yp  = y16 + ((size_t)b << 20) + d;     // + t*1024

  const int ct = tid >> 4;             // 0..15
  const int cs = (tid & 15) * 4;       // 0..60
  const float* bcbase = dbc + (size_t)b * 163840 + (size_t)ct * 160 + cs;

  const int tt_r = lane >> 2;
  const int c0   = (lane & 3) << 4;

  {
    *(float4*)&BC[0][0][ct][cs] = *(const float4*)(bcbase + 32);
    *(float4*)&BC[0][1][ct][cs] = *(const float4*)(bcbase + 96);
  }
  __syncthreads();

  float h = 0.f;
  for (int t0 = 0; t0 < 1024; t0 += 16) {
    const int p = (t0 >> 4) & 1;
    const int tn = (t0 + 16 < 1024) ? (t0 + 16) : t0;
    float4 nb = *(const float4*)(bcbase + (size_t)tn * 160 + 32);
    float4 nc = *(const float4*)(bcbase + (size_t)tn * 160 + 96);

    float4 dq[4], xq[4];
    #pragma unroll
    for (int i = 0; i < 4; ++i) {
      dq[i] = *(const float4*)(dtp + t0 + i*4);
      xq[i] = *(const float4*)(xp  + t0 + i*4);
    }
    float zs  = (float)zsp[t0 + tt_r] * Y_SCALE;   // exact 2^14 fold
    float xvl = xp[t0 + tt_r];
    const float* dtv = reinterpret_cast<const float*>(dq);
    const float* xv  = reinterpret_cast<const float*>(xq);

    float dA[16], ub[16], Cv[16];
    #pragma unroll
    for (int tt = 0; tt < 16; ++tt) {
      float Bv = BC[p][0][tt][lane];
      Cv[tt]   = BC[p][1][tt][lane];
      dA[tt] = __expf(dtv[tt] * a);
      ub[tt] = dtv[tt] * xv[tt] * Bv;
    }
    #pragma unroll
    for (int tt = 0; tt < 16; ++tt) {
      h = fmaf(h, dA[tt], ub[tt]);
      Pw[tt][lane] = h * Cv[tt];
    }

    float4 s0 = *(const float4*)&Pw[tt_r][c0];
    float4 s1 = *(const float4*)&Pw[tt_r][c0 + 4];
    float4 s2 = *(const float4*)&Pw[tt_r][c0 + 8];
    float4 s3 = *(const float4*)&Pw[tt_r][c0 + 12];
    float r = ((s0.x + s0.y) + (s0.z + s0.w))
            + ((s1.x + s1.y) + (s1.z + s1.w))
            + ((s2.x + s2.y) + (s2.z + s2.w))
            + ((s3.x + s3.y) + (s3.z + s3.w));
    r += __shfl_xor(r, 1, 64);
    r += __shfl_xor(r, 2, 64);
    if ((lane & 3) == 0)
      yp[(size_t)(t0 + tt_r) << 10] = (_Float16)(fmaf(xvl, dpv, r) * zs);

    *(float4*)&BC[1 - p][0][ct][cs] = nb;
    *(float4*)&BC[1 - p][1][ct][cs] = nc;
    __syncthreads();
  }
}

// out[b,c] = h[b,L-1,:] . fc_w[c,:] + fc_b[c]; h is fp32 [4096][512]
__global__ void head_kernel(const float* __restrict__ h,
                            const float* __restrict__ fc_w,
                            const float* __restrict__ fc_b,
                            float* __restrict__ out)
{
  int bc = blockIdx.x;            // 0..11
  int b = bc / 3, c = bc % 3;
  int lane = threadIdx.x;
  const float* hr = h + (size_t)(b*1024 + 1023) * 512;
  const float* wr = fc_w + c*512;
  float s = 0.f;
  #pragma unroll
  for (int i = 0; i < 8; ++i) s = fmaf(hr[lane + i*64], wr[lane + i*64], s);
  #pragma unroll
  for (int o = 32; o > 0; o >>= 1) s += __shfl_xor(s, o, 64);
  if (lane == 0) out[b*3 + c] = s + fc_b[c];
}

extern "C" void kernel_launch(void* const* d_in, const int* in_sizes, int n_in,
                              void* d_out, int out_size, void* d_ws, size_t ws_size,
                              hipStream_t stream)
{
  const float* x        = (const float*)d_in[0];
  const float* exp_w    = (const float*)d_in[1];
  const float* exp_b    = (const float*)d_in[2];
  const float* in_w     = (const float*)d_in[3];
  const float* conv_w   = (const float*)d_in[4];
  const float* conv_b   = (const float*)d_in[5];
  const float* xproj_w  = (const float*)d_in[6];
  const float* dtproj_w = (const float*)d_in[7];
  const float* dtproj_b = (const float*)d_in[8];
  const float* A_log    = (const float*)d_in[9];
  const float* Dp       = (const float*)d_in[10];
  const float* out_w    = (const float*)d_in[11];
  const float* fc_w     = (const float*)d_in[12];
  const float* fc_b     = (const float*)d_in[13];
  float* out = (float*)d_out;

  // Workspace layout (byte offsets), 72 MB total.
  // 4..20 MB region sequentially reused: xcpre -> dtT -> hf32 (l1 out).
  char* ws = (char*)d_ws;
  _Float16* hf16  = (_Float16*)(ws);                          //  4 MB [4096][512] f16
  float*    xcpre = (float*)   (ws + ((size_t)4  << 20));     // 16 MB [4096][1024]
  float*    dtT   = (float*)   (ws + ((size_t)4  << 20));     // 16 MB [1024][4096] (reuse)
  float*    hf32  = (float*)   (ws + ((size_t)4  << 20));     //  8 MB [4096][512] (reuse, l1)
  float*    xcT   = (float*)   (ws + ((size_t)20 << 20));     // 16 MB [1024][4096]
  _Float16* zsT   = (_Float16*)(ws + ((size_t)36 << 20));     //  8 MB [1024][4096]
  float*    dbc   = (float*)   (ws + ((size_t)44 << 20));     //  2.6 MB [4096][160]
  _Float16* dtr16 = (_Float16*)(ws + ((size_t)47 << 20));     //  0.25 MB [4096][32]
  _Float16* xc16  = (_Float16*)(ws + ((size_t)48 << 20));     //  8 MB [4096][1024]
  _Float16* y16   = (_Float16*)(ws + ((size_t)56 << 20));     //  8 MB [4096][1024]
  _Float16* w16   = (_Float16*)(ws + ((size_t)64 << 20));     //  7.9 MB f16 pool

  _Float16* exp16 = w16;                 // [512][128]
  _Float16* in16  = w16 + 65536;         // [2][2048][512]
  _Float16* xp16  = w16 + 2162688;       // [2][160][1024]
  _Float16* dt16  = w16 + 2490368;       // [2][1024][32]
  _Float16* out16 = w16 + 2555904;       // [2][512][1024]
  _Float16* x16   = w16 + 3604480;       // [4096][128]

  dim3 blk(256);

  // one-shot f16 conversion of all weights + x (4128768 elems, 4032 blocks)
  wcvt_kernel<<<4032, blk, 0, stream>>>(exp_w, in_w, xproj_w, dtproj_w, out_w,
                                        x, w16);

  // expand: hf16 = f16(x @ exp_w^T + exp_b)   [4096,512] K=128. 512 blocks.
  gemm_mfma<64,0,1,0><<<dim3(8,64), blk, 0, stream>>>(x16, 128, exp16, exp_b,
                                                      hf16, 512, 512, 128, 1.f,
                                                      nullptr);

  for (int l = 0; l < 2; ++l) {
    const float is = l ? (1.f / H1_SCALE) : 1.f;     // undo h1 scaling (exact)
    // fused in_proj: xcpre fp32 + zsT f16 (LDS-transposed). N=2048 K=512.
    gemm_mfma<128,0,0,1><<<dim3(16,64), blk, 0, stream>>>(hf16, 512,
                                                          in16 + (size_t)l*1048576,
                                                          nullptr, xcpre, 1024,
                                                          2048, 512, is, zsT);
    // conv + silu -> xcT (fp32, scan) + xc16 (f16, xproj A)
    conv_t_kernel<<<1024, blk, 0, stream>>>(xcpre, conv_w + l*2048, conv_b + l*1024,
                                            xcT, xc16);
    // xproj (MODE 2): dtr16 f16 [4096][32] + dbc fp32 [4096][160]. K=1024.
    gemm_mfma<64,0,0,2><<<dim3(3,64), blk, 0, stream>>>(xc16, 1024,
                                                        xp16 + (size_t)l*163840,
                                                        nullptr, dbc, 160,
                                                        160, 1024, 1.f, dtr16);
    // dtproj (MODE 3): dtT [1024][4096] softplus, LDS-transposed stores. K=32.
    gemm_mfma<64,0,0,3><<<dim3(16,64), blk, 0, stream>>>(dtr16, 32,
                                                         dt16 + (size_t)l*32768,
                                                         dtproj_b + l*1024,
                                                         dtT, 4096, 1024, 32, 1.f,
                                                         nullptr);
    // selective scan; y16 = f16((scan + x*Dp)*silu(z) * 2^14) [bl][d]
    scan_kernel<<<1024, blk, 0, stream>>>(dtT, xcT, zsT, dbc,
                                          A_log + (size_t)l*65536, Dp + l*1024, y16);
    // out_proj: l0 -> hf16 = f16(h1 * 2^8); l1 -> hf32 fp32 for the head.
    if (l == 0)
      gemm_mfma<64,0,1,0><<<dim3(8,64), blk, 0, stream>>>(y16, 1024,
                                                          out16, nullptr,
                                                          hf16, 512, 512, 1024,
                                                          H1_SCALE / Y_SCALE,
                                                          nullptr);
    else
      gemm_mfma<64,0,0,0><<<dim3(8,64), blk, 0, stream>>>(y16, 1024,
                                                          out16 + 524288, nullptr,
                                                          hf32, 512, 512, 1024,
                                                          1.f / Y_SCALE, nullptr);
  }

  head_kernel<<<12, 64, 0, stream>>>(hf32, fc_w, fc_b, out);
}

// Round 17
// 453.193 us; speedup vs baseline: 1.1264x; 1.0194x over previous
//
#include <hip/hip_runtime.h>
#include <math.h>

// Problem constants: B=4, L=1024, D_IN=128, D_MODEL=512, N_LAYERS=2,
// N_CLASSES=3, D_INNER=1024, D_STATE=64, D_CONV=2, DT_RANK=32, BL=4096.
//
// Precision plan: all GEMM operands f16 (conversions hoisted upstream).
// Layer-1 residual h f16 scaled by 2^8 (exact). y scaled by 2^14 at the
// scan store. Final head works from y16(l1) directly with fp32 weights.
//
// R17: (a) scan reads B/C directly from global, per-lane coalesced
// (dbc[b][t][32+lane] = 64 consecutive floats/instr — R7's pattern, NOT
// R11's strided-row disaster) -> BC LDS tile + its barrier deleted; scan
// is barrier-free, LDS/wave-chunk 18->8 KB. (b) out_proj(l1) + head
// replaced by one 12-block head2 kernel (only 4 rows of h ever mattered).

using half8  = __attribute__((ext_vector_type(8))) _Float16;
using half4v = __attribute__((ext_vector_type(4))) _Float16;
using f32x4  = __attribute__((ext_vector_type(4))) float;

#define Y_SCALE 16384.0f   // 2^14
#define H1_SCALE 256.0f    // 2^8

__device__ __forceinline__ float silu_f(float v) {
  return v / (1.f + __expf(-v));
}

// ---------------------------------------------------------------------------
// One-shot fp32 -> f16 conversion of all weights + x into the w16 pool.
//   exp_w 0..65536 | in_w ..2162688 | xproj_w ..2490368 | dtproj_w ..2555904
//   | out_w ..3604480 | x ..4128768
// ---------------------------------------------------------------------------
__global__ void wcvt_kernel(const float* __restrict__ exp_w,
                            const float* __restrict__ in_w,
                            const float* __restrict__ xproj_w,
                            const float* __restrict__ dtproj_w,
                            const float* __restrict__ out_w,
                            const float* __restrict__ x,
                            _Float16* __restrict__ w16)
{
  size_t gi = ((size_t)blockIdx.x * 256 + threadIdx.x) * 4;
  const float* src; size_t off;
  if      (gi < 65536)   { src = exp_w;    off = gi; }
  else if (gi < 2162688) { src = in_w;     off = gi - 65536; }
  else if (gi < 2490368) { src = xproj_w;  off = gi - 2162688; }
  else if (gi < 2555904) { src = dtproj_w; off = gi - 2490368; }
  else if (gi < 3604480) { src = out_w;    off = gi - 2555904; }
  else                   { src = x;        off = gi - 3604480; }
  float4 v = *(const float4*)(src + off);
  half4v h;
  h[0] = (_Float16)v.x; h[1] = (_Float16)v.y;
  h[2] = (_Float16)v.z; h[3] = (_Float16)v.w;
  *(half4v*)(w16 + gi) = h;
}

// ---------------------------------------------------------------------------
// f16 MFMA GEMM, 64 x BN tile. Block 256 thr = 4 waves; wave-tile 32 x (BN/2),
// MI=2 m-frags. BK=32. A and W both f16: staging is pure half8 load ->
// ds_write. Modes: 0 plain / 1 in_proj fused / 2 xproj split / 3 dtproj
// transposed-softplus.
// MFMA layouts (m89/m120-verified): A-frag A[m=lane&15][k=q*8+j],
// B-frag B[k=q*8+j][n=lane&15], D: col(n)=lane&15, row(m)=q*4+r.
// ---------------------------------------------------------------------------
template<int BN, int ACT, int OF16, int MODE>
__global__ __launch_bounds__(256)
void gemm_mfma(const _Float16* __restrict__ A, int lda,
               const _Float16* __restrict__ W,
               const float* __restrict__ bias,
               void* __restrict__ Cv, int ldc,
               int N, int K, float oscale,
               void* __restrict__ Cv2)
{
  constexpr int NF = BN / 32;            // n-frags per wave
  __shared__ _Float16 As[64 * 40];       // [m][k], row stride 40 f16 (80 B)
  __shared__ _Float16 Ws[BN * 40];       // [n][k]
  __shared__ _Float16 Tz[(MODE == 1) ? 128 * 72 : 8];   // z-half transpose
  __shared__ float    Td[(MODE == 3) ? 64 * 68  : 2];   // dtproj transpose
  const int tid  = threadIdx.x;
  const int lane = tid & 63;
  const int wid  = tid >> 6;
  const int wm   = wid & 1, wn = wid >> 1;   // wave-tile: 32 m x BN/2 n
  const int m0   = blockIdx.y * 64;
  const int n0   = blockIdx.x * BN;
  const int q    = lane >> 4, l16 = lane & 15;

  // A staging: 64 rows, 4 threads/row, 8 halfs each
  const int ar  = tid >> 2;
  const int akq = (tid & 3) * 8;
  // W staging: BN=128: 2 thr/row x 16 halfs; BN=64: 4 thr/row x 8 halfs
  const int wr  = (BN == 128) ? (tid >> 1) : (tid >> 2);
  const int wkq = (BN == 128) ? ((tid & 1) * 16) : ((tid & 3) * 8);
  const int wrow = n0 + wr;
  const bool wv  = (wrow < N);

  const _Float16* Wp = W + (size_t)wrow * K;
  const size_t aoff = (size_t)(m0 + ar) * lda + akq;

  half8 zh;
  #pragma unroll
  for (int i = 0; i < 8; ++i) zh[i] = (_Float16)0.f;

  // initial loads (k0 = 0)
  half8 rah = *(const half8*)(A + aoff);
  half8 rwh0 = zh, rwh1 = zh;
  if (wv) {
    rwh0 = *(const half8*)(Wp + wkq);
    if (BN == 128) rwh1 = *(const half8*)(Wp + wkq + 8);
  }

  f32x4 acc[2][NF];
  #pragma unroll
  for (int mi = 0; mi < 2; ++mi)
    #pragma unroll
    for (int ni = 0; ni < NF; ++ni)
      acc[mi][ni] = (f32x4){0.f, 0.f, 0.f, 0.f};

  for (int k0 = 0; k0 < K; k0 += 32) {
    if (k0) __syncthreads();
    *(half8*)&As[ar * 40 + akq] = rah;
    *(half8*)&Ws[wr * 40 + wkq] = rwh0;
    if (BN == 128) *(half8*)&Ws[wr * 40 + wkq + 8] = rwh1;
    __syncthreads();

    if (k0 + 32 < K) {            // prefetch next chunk
      const int kn = k0 + 32;
      rah = *(const half8*)(A + aoff + kn);
      if (wv) {
        rwh0 = *(const half8*)(Wp + kn + wkq);
        if (BN == 128) rwh1 = *(const half8*)(Wp + kn + wkq + 8);
      }
    }

    half8 af[2], wf[NF];
    #pragma unroll
    for (int mi = 0; mi < 2; ++mi)
      af[mi] = *(const half8*)&As[(wm * 32 + mi * 16 + l16) * 40 + q * 8];
    #pragma unroll
    for (int ni = 0; ni < NF; ++ni)
      wf[ni] = *(const half8*)&Ws[(wn * (BN / 2) + ni * 16 + l16) * 40 + q * 8];
    #pragma unroll
    for (int mi = 0; mi < 2; ++mi)
      #pragma unroll
      for (int ni = 0; ni < NF; ++ni)
        acc[mi][ni] = __builtin_amdgcn_mfma_f32_16x16x32_f16(af[mi], wf[ni],
                                                             acc[mi][ni], 0, 0, 0);
  }

  float*    Cf = (float*)Cv;
  _Float16* Ch = (_Float16*)Cv;

  if (MODE == 1) {
    if (n0 < 1024) {
      // xc half: fp32 [M][1024]
      #pragma unroll
      for (int ni = 0; ni < NF; ++ni) {
        const int n = n0 + wn * (BN / 2) + ni * 16 + l16;
        #pragma unroll
        for (int mi = 0; mi < 2; ++mi) {
          const int mb = m0 + wm * 32 + mi * 16 + q * 4;
          #pragma unroll
          for (int r = 0; r < 4; ++r)
            Cf[(size_t)(mb + r) * 1024 + n] = acc[mi][ni][r] * oscale;
        }
      }
    } else {
      // z half: silu -> f16, LDS transpose, coalesced 16B row stores
      _Float16* Ch2 = (_Float16*)Cv2;
      __syncthreads();
      #pragma unroll
      for (int ni = 0; ni < NF; ++ni) {
        const int nnl = wn * (BN / 2) + ni * 16 + l16;   // 0..127 local
        #pragma unroll
        for (int mi = 0; mi < 2; ++mi) {
          const int mbl = wm * 32 + mi * 16 + q * 4;     // 0..63 local
          half4v h4;
          #pragma unroll
          for (int r = 0; r < 4; ++r)
            h4[r] = (_Float16)silu_f(acc[mi][ni][r] * oscale);
          *(half4v*)&Tz[nnl * 72 + mbl] = h4;
        }
      }
      __syncthreads();
      const int sr = tid >> 3;          // 0..31
      const int sc = (tid & 7) * 8;     // halfs 0..56
      #pragma unroll
      for (int rd = 0; rd < 4; ++rd) {
        const int row = rd * 32 + sr;
        half8 v = *(const half8*)&Tz[row * 72 + sc];
        *(half8*)&Ch2[(size_t)(n0 - 1024 + row) * 4096 + m0 + sc] = v;
      }
    }
    return;
  }

  if (MODE == 2) {
    // xproj: n<32 -> dtr16 f16 [M][32]; 32<=n<160 -> dbc fp32 [M][160]
    _Float16* dtr = (_Float16*)Cv2;
    #pragma unroll
    for (int ni = 0; ni < NF; ++ni) {
      const int n = n0 + wn * (BN / 2) + ni * 16 + l16;
      #pragma unroll
      for (int mi = 0; mi < 2; ++mi) {
        const int mb = m0 + wm * 32 + mi * 16 + q * 4;
        if (n < 32) {
          #pragma unroll
          for (int r = 0; r < 4; ++r)
            dtr[(size_t)(mb + r) * 32 + n] = (_Float16)acc[mi][ni][r];
        } else if (n < 160) {
          #pragma unroll
          for (int r = 0; r < 4; ++r)
            Cf[(size_t)(mb + r) * 160 + n] = acc[mi][ni][r];
        }
      }
    }
    return;
  }

  if (MODE == 3) {
    // dtproj: softplus(acc*oscale + bias) -> fp32 [N][4096] via LDS transpose
    __syncthreads();
    #pragma unroll
    for (int ni = 0; ni < NF; ++ni) {
      const int nnl = wn * (BN / 2) + ni * 16 + l16;     // 0..63 local
      const float bv = (bias != nullptr) ? bias[n0 + nnl] : 0.f;
      #pragma unroll
      for (int mi = 0; mi < 2; ++mi) {
        const int mbl = wm * 32 + mi * 16 + q * 4;       // 0..63 local
        float o[4];
        #pragma unroll
        for (int r = 0; r < 4; ++r) {
          float v = acc[mi][ni][r] * oscale + bv;
          o[r] = (v > 20.f) ? v : log1pf(__expf(v));     // softplus
        }
        *(float4*)&Td[nnl * 68 + mbl] = make_float4(o[0], o[1], o[2], o[3]);
      }
    }
    __syncthreads();
    const int sr = tid >> 4;            // 0..15
    const int sc = (tid & 15) * 4;      // floats 0..60
    #pragma unroll
    for (int rd = 0; rd < 4; ++rd) {
      const int row = rd * 16 + sr;
      float4 v = *(const float4*)&Td[row * 68 + sc];
      *(float4*)&Cf[(size_t)(n0 + row) * 4096 + m0 + sc] = v;
    }
    return;
  }

  // MODE 0 epilogue
  #pragma unroll
  for (int ni = 0; ni < NF; ++ni) {
    const int n = n0 + wn * (BN / 2) + ni * 16 + l16;
    if (n < N) {
      const float bv = (bias != nullptr) ? bias[n] : 0.f;
      #pragma unroll
      for (int mi = 0; mi < 2; ++mi) {
        const int mb = m0 + wm * 32 + mi * 16 + q * 4;
        #pragma unroll
        for (int r = 0; r < 4; ++r) {
          float v = acc[mi][ni][r] * oscale + bv;
          if (ACT == 1) v = (v > 20.f) ? v : log1pf(__expf(v));
          if (ACT == 2) v = silu_f(v);
          size_t off = (size_t)(mb + r) * ldc + n;
          if (OF16) Ch[off] = (_Float16)v;
          else      Cf[off] = v;
        }
      }
    }
  }
}

// ---------------------------------------------------------------------------
// Depthwise causal conv (D_CONV=2) + silu, 64x64 LDS transpose.
// in : xcp [4096 bl][1024 d] fp32
// out: xcT [1024 d][4096 bl] fp32 (scan input)  +  xcf [4096 bl][1024 d] f16
// ---------------------------------------------------------------------------
__global__ void conv_t_kernel(const float* __restrict__ xcp,
                              const float* __restrict__ cw,   // [1024][2]
                              const float* __restrict__ cb,   // [1024]
                              float* __restrict__ xcT,
                              _Float16* __restrict__ xcf)
{
  __shared__ float tile[64][65];
  const int blk = blockIdx.x;            // b*256 + tt*16 + dd
  const int b  = blk >> 8;
  const int tt = (blk >> 4) & 15;
  const int dd = blk & 15;
  const int t0 = tt * 64, d0 = dd * 64;
  const int tid = threadIdx.x;

  #pragma unroll
  for (int i = 0; i < 16; ++i) {
    int idx = i * 256 + tid;
    int t = idx >> 6, d = idx & 63;
    int gt = t0 + t;
    size_t rcur = ((size_t)(b * 1024 + gt) << 10) + d0 + d;
    float cur  = xcp[rcur];
    float prev = (gt > 0) ? xcp[rcur - 1024] : 0.f;
    float v = fmaf(prev, cw[(d0+d)*2], fmaf(cur, cw[(d0+d)*2 + 1], cb[d0+d]));
    float sv = silu_f(v);
    tile[t][d] = sv;
    xcf[rcur] = (_Float16)sv;
  }
  __syncthreads();
  #pragma unroll
  for (int i = 0; i < 16; ++i) {
    int idx = i * 256 + tid;
    int d = idx >> 6, t = idx & 63;
    xcT[((size_t)(d0 + d) << 12) + b * 1024 + t0 + t] = tile[t][d];
  }
}

// ---------------------------------------------------------------------------
// Selective scan, time-major. One wave per (b,d), lane = s (D_STATE=64).
// R17: BARRIER-FREE. B/C read directly from global, per-lane coalesced
// (dbc[b][t][32+lane]: 64 consecutive floats = 1 coalesced 256B transaction
// per t per tensor — the R7 pattern). P tile is wave-private (lgkmcnt
// ordering only). XCD swizzle + direct f16 y store (x 2^14 exact) kept.
// ---------------------------------------------------------------------------
__global__ __launch_bounds__(256, 4)
void scan_kernel(const float* __restrict__ dtT,     // [1024][4096]
                 const float* __restrict__ xcT,     // [1024][4096]
                 const _Float16* __restrict__ zsT,  // [1024][4096], silu(z), f16
                 const float* __restrict__ dbc,     // [B][1024][160]; B@+32, C@+96
                 const float* __restrict__ A_log,   // [1024][64]
                 const float* __restrict__ Dp,      // [1024]
                 _Float16* __restrict__ y16)        // [4096 bl][1024 d], y*2^14
{
  __shared__ float P[4][16][68];       // per-wave reduction tile (wave-private)
  const int tid  = threadIdx.x;
  const int lane = tid & 63;
  const int wrp  = tid >> 6;
  const int rb   = blockIdx.x;
  const int bswz = ((rb & 7) << 7) | (rb >> 3);          // XCD swizzle
  const int wid  = __builtin_amdgcn_readfirstlane(bswz * 4 + wrp);
  const int b = wid >> 10;
  const int d = wid & 1023;
  float (*Pw)[68] = P[wrp];

  const float a   = -__expf(A_log[d*64 + lane]);
  const float dpv = Dp[d];
  const size_t row = ((size_t)d << 12) + b * 1024;
  const float*    dtp = dtT + row;
  const float*    xp  = xcT + row;
  const _Float16* zsp = zsT + row;
  _Float16*       yp  = y16 + ((size_t)b << 20) + d;     // + t*1024
  const float*    bcp = dbc + (size_t)b * 163840 + lane; // + t*160 (+32/+96)

  const int tt_r = lane >> 2;
  const int c0   = (lane & 3) << 4;

  float h = 0.f;
  for (int t0 = 0; t0 < 1024; t0 += 16) {
    // ---- chunk loads: all independent, issue together ----
    const float* bp = bcp + (size_t)t0 * 160;
    float Bv[16], Cv[16];
    #pragma unroll
    for (int tt = 0; tt < 16; ++tt) {
      Bv[tt] = bp[tt * 160 + 32];     // coalesced 64-lane run
      Cv[tt] = bp[tt * 160 + 96];
    }
    float4 dq[4], xq[4];
    #pragma unroll
    for (int i = 0; i < 4; ++i) {
      dq[i] = *(const float4*)(dtp + t0 + i*4);
      xq[i] = *(const float4*)(xp  + t0 + i*4);
    }
    float zs  = (float)zsp[t0 + tt_r] * Y_SCALE;   // exact 2^14 fold
    float xvl = xp[t0 + tt_r];
    const float* dtv = reinterpret_cast<const float*>(dq);
    const float* xv  = reinterpret_cast<const float*>(xq);

    // ---- parallel phase: everything h-independent ----
    float dA[16], ub[16];
    #pragma unroll
    for (int tt = 0; tt < 16; ++tt) {
      dA[tt] = __expf(dtv[tt] * a);
      ub[tt] = dtv[tt] * xv[tt] * Bv[tt];
    }
    // ---- serial recurrence: fma -> mul -> ds_write per t ----
    #pragma unroll
    for (int tt = 0; tt < 16; ++tt) {
      h = fmaf(h, dA[tt], ub[tt]);
      Pw[tt][lane] = h * Cv[tt];
    }

    // ---- batched reduction: lane L sums 16 states of timestep L>>2 ----
    float4 s0 = *(const float4*)&Pw[tt_r][c0];
    float4 s1 = *(const float4*)&Pw[tt_r][c0 + 4];
    float4 s2 = *(const float4*)&Pw[tt_r][c0 + 8];
    float4 s3 = *(const float4*)&Pw[tt_r][c0 + 12];
    float r = ((s0.x + s0.y) + (s0.z + s0.w))
            + ((s1.x + s1.y) + (s1.z + s1.w))
            + ((s2.x + s2.y) + (s2.z + s2.w))
            + ((s3.x + s3.y) + (s3.z + s3.w));
    r += __shfl_xor(r, 1, 64);
    r += __shfl_xor(r, 2, 64);
    if ((lane & 3) == 0)
      yp[(size_t)(t0 + tt_r) << 10] = (_Float16)(fmaf(xvl, dpv, r) * zs);
    // no __syncthreads: P is wave-private, ordered by lgkmcnt.
  }
}

// ---------------------------------------------------------------------------
// Fused out_proj(l1)+fc head: only h[b, L-1, :] ever reaches the output, so
// out[b,c] = (sum_di y16l1[b*1024+1023][di] * w2[c][di]) * 2^-14 + fc_b[c],
// w2[c][di] = sum_dm fc_w[c][dm] * out_w1[dm][di]   (fp32 weights).
// 12 blocks (b,c) x 256 threads; thread covers 4 di columns (coalesced f4).
// ---------------------------------------------------------------------------
__global__ void head2_kernel(const _Float16* __restrict__ y16,
                             const float* __restrict__ out_w1,  // [512][1024]
                             const float* __restrict__ fc_w,    // [3][512]
                             const float* __restrict__ fc_b,
                             float* __restrict__ out)
{
  __shared__ float red[4];
  const int bc = blockIdx.x;            // 0..11
  const int b = bc / 3, c = bc % 3;
  const int tid = threadIdx.x;
  const int lane = tid & 63, wv = tid >> 6;

  float4 w2 = make_float4(0.f, 0.f, 0.f, 0.f);
  const float* fcr = fc_w + c * 512;
  const float* owp = out_w1 + tid * 4;
  for (int dm = 0; dm < 512; ++dm) {
    float f = fcr[dm];
    float4 o = *(const float4*)(owp + (size_t)dm * 1024);
    w2.x = fmaf(f, o.x, w2.x); w2.y = fmaf(f, o.y, w2.y);
    w2.z = fmaf(f, o.z, w2.z); w2.w = fmaf(f, o.w, w2.w);
  }
  const _Float16* yr = y16 + ((size_t)(b * 1024 + 1023) << 10) + tid * 4;
  half4v yv = *(const half4v*)yr;
  float s = (float)yv[0] * w2.x + (float)yv[1] * w2.y
          + (float)yv[2] * w2.z + (float)yv[3] * w2.w;
  #pragma unroll
  for (int o = 32; o > 0; o >>= 1) s += __shfl_xor(s, o, 64);
  if (lane == 0) red[wv] = s;
  __syncthreads();
  if (tid == 0)
    out[b * 3 + c] = (red[0] + red[1] + red[2] + red[3]) * (1.f / Y_SCALE)
                     + fc_b[c];
}

extern "C" void kernel_launch(void* const* d_in, const int* in_sizes, int n_in,
                              void* d_out, int out_size, void* d_ws, size_t ws_size,
                              hipStream_t stream)
{
  const float* x        = (const float*)d_in[0];
  const float* exp_w    = (const float*)d_in[1];
  const float* exp_b    = (const float*)d_in[2];
  const float* in_w     = (const float*)d_in[3];
  const float* conv_w   = (const float*)d_in[4];
  const float* conv_b   = (const float*)d_in[5];
  const float* xproj_w  = (const float*)d_in[6];
  const float* dtproj_w = (const float*)d_in[7];
  const float* dtproj_b = (const float*)d_in[8];
  const float* A_log    = (const float*)d_in[9];
  const float* Dp       = (const float*)d_in[10];
  const float* out_w    = (const float*)d_in[11];
  const float* fc_w     = (const float*)d_in[12];
  const float* fc_b     = (const float*)d_in[13];
  float* out = (float*)d_out;

  // Workspace layout (byte offsets), 72 MB total.
  // 4..20 MB region sequentially reused: xcpre -> dtT.
  char* ws = (char*)d_ws;
  _Float16* hf16  = (_Float16*)(ws);                          //  4 MB [4096][512] f16
  float*    xcpre = (float*)   (ws + ((size_t)4  << 20));     // 16 MB [4096][1024]
  float*    dtT   = (float*)   (ws + ((size_t)4  << 20));     // 16 MB [1024][4096] (reuse)
  float*    xcT   = (float*)   (ws + ((size_t)20 << 20));     // 16 MB [1024][4096]
  _Float16* zsT   = (_Float16*)(ws + ((size_t)36 << 20));     //  8 MB [1024][4096]
  float*    dbc   = (float*)   (ws + ((size_t)44 << 20));     //  2.6 MB [4096][160]
  _Float16* dtr16 = (_Float16*)(ws + ((size_t)47 << 20));     //  0.25 MB [4096][32]
  _Float16* xc16  = (_Float16*)(ws + ((size_t)48 << 20));     //  8 MB [4096][1024]
  _Float16* y16   = (_Float16*)(ws + ((size_t)56 << 20));     //  8 MB [4096][1024]
  _Float16* w16   = (_Float16*)(ws + ((size_t)64 << 20));     //  7.9 MB f16 pool

  _Float16* exp16 = w16;                 // [512][128]
  _Float16* in16  = w16 + 65536;         // [2][2048][512]
  _Float16* xp16  = w16 + 2162688;       // [2][160][1024]
  _Float16* dt16  = w16 + 2490368;       // [2][1024][32]
  _Float16* out16 = w16 + 2555904;       // [2][512][1024]
  _Float16* x16   = w16 + 3604480;       // [4096][128]

  dim3 blk(256);

  // one-shot f16 conversion of all weights + x (4128768 elems, 4032 blocks)
  wcvt_kernel<<<4032, blk, 0, stream>>>(exp_w, in_w, xproj_w, dtproj_w, out_w,
                                        x, w16);

  // expand: hf16 = f16(x @ exp_w^T + exp_b)   [4096,512] K=128. 512 blocks.
  gemm_mfma<64,0,1,0><<<dim3(8,64), blk, 0, stream>>>(x16, 128, exp16, exp_b,
                                                      hf16, 512, 512, 128, 1.f,
                                                      nullptr);

  for (int l = 0; l < 2; ++l) {
    const float is = l ? (1.f / H1_SCALE) : 1.f;     // undo h1 scaling (exact)
    // fused in_proj: xcpre fp32 + zsT f16 (LDS-transposed). N=2048 K=512.
    gemm_mfma<128,0,0,1><<<dim3(16,64), blk, 0, stream>>>(hf16, 512,
                                                          in16 + (size_t)l*1048576,
                                                          nullptr, xcpre, 1024,
                                                          2048, 512, is, zsT);
    // conv + silu -> xcT (fp32, scan) + xc16 (f16, xproj A)
    conv_t_kernel<<<1024, blk, 0, stream>>>(xcpre, conv_w + l*2048, conv_b + l*1024,
                                            xcT, xc16);
    // xproj (MODE 2): dtr16 f16 [4096][32] + dbc fp32 [4096][160]. K=1024.
    gemm_mfma<64,0,0,2><<<dim3(3,64), blk, 0, stream>>>(xc16, 1024,
                                                        xp16 + (size_t)l*163840,
                                                        nullptr, dbc, 160,
                                                        160, 1024, 1.f, dtr16);
    // dtproj (MODE 3): dtT [1024][4096] softplus, LDS-transposed stores. K=32.
    gemm_mfma<64,0,0,3><<<dim3(16,64), blk, 0, stream>>>(dtr16, 32,
                                                         dt16 + (size_t)l*32768,
                                                         dtproj_b + l*1024,
                                                         dtT, 4096, 1024, 32, 1.f,
                                                         nullptr);
    // selective scan (barrier-free); y16 = f16((scan + x*Dp)*silu(z) * 2^14)
    scan_kernel<<<1024, blk, 0, stream>>>(dtT, xcT, zsT, dbc,
                                          A_log + (size_t)l*65536, Dp + l*1024, y16);
    // out_proj only for layer 0 (layer-1 h is only needed at t = L-1 -> head2)
    if (l == 0)
      gemm_mfma<64,0,1,0><<<dim3(8,64), blk, 0, stream>>>(y16, 1024,
                                                          out16, nullptr,
                                                          hf16, 512, 512, 1024,
                                                          H1_SCALE / Y_SCALE,
                                                          nullptr);
  }

  // fused out_proj(l1) + fc head from y16(l1) directly (fp32 weights)
  head2_kernel<<<12, blk, 0, stream>>>(y16, out_w + (size_t)512*1024,
                                       fc_w, fc_b, out);
}

// Round 19
// 440.013 us; speedup vs baseline: 1.1602x; 1.0300x over previous
//
#include <hip/hip_runtime.h>
#include <math.h>

// Problem constants: B=4, L=1024, D_IN=128, D_MODEL=512, N_LAYERS=2,
// N_CLASSES=3, D_INNER=1024, D_STATE=64, D_CONV=2, DT_RANK=32, BL=4096.
//
// Precision plan: all GEMM operands f16 (conversions hoisted upstream).
// Layer-1 residual h f16 scaled by 2^8 (exact). y scaled by 2^14 at the
// scan store. Head works from y16(l1) directly with fp32 weights.
//
// R18b: BK=64 for K>=512 GEMMs; MODE-1's Tz aliases Ws; xcpre f16.
// Fixed W-staging arithmetic: WH = BK/WTR (was BK*BN/512 — zero-length
// array for (64,32) and silent half-tile staging for (128,64)).

using half8  = __attribute__((ext_vector_type(8))) _Float16;
using half4v = __attribute__((ext_vector_type(4))) _Float16;
using f32x4  = __attribute__((ext_vector_type(4))) float;

#define Y_SCALE 16384.0f   // 2^14
#define H1_SCALE 256.0f    // 2^8

__device__ __forceinline__ float silu_f(float v) {
  return v / (1.f + __expf(-v));
}

// ---------------------------------------------------------------------------
// One-shot fp32 -> f16 conversion of all weights + x into the w16 pool.
//   exp_w 0..65536 | in_w ..2162688 | xproj_w ..2490368 | dtproj_w ..2555904
//   | out_w ..3604480 | x ..4128768
// ---------------------------------------------------------------------------
__global__ void wcvt_kernel(const float* __restrict__ exp_w,
                            const float* __restrict__ in_w,
                            const float* __restrict__ xproj_w,
                            const float* __restrict__ dtproj_w,
                            const float* __restrict__ out_w,
                            const float* __restrict__ x,
                            _Float16* __restrict__ w16)
{
  size_t gi = ((size_t)blockIdx.x * 256 + threadIdx.x) * 4;
  const float* src; size_t off;
  if      (gi < 65536)   { src = exp_w;    off = gi; }
  else if (gi < 2162688) { src = in_w;     off = gi - 65536; }
  else if (gi < 2490368) { src = xproj_w;  off = gi - 2162688; }
  else if (gi < 2555904) { src = dtproj_w; off = gi - 2490368; }
  else if (gi < 3604480) { src = out_w;    off = gi - 2555904; }
  else                   { src = x;        off = gi - 3604480; }
  float4 v = *(const float4*)(src + off);
  half4v h;
  h[0] = (_Float16)v.x; h[1] = (_Float16)v.y;
  h[2] = (_Float16)v.z; h[3] = (_Float16)v.w;
  *(half4v*)(w16 + gi) = h;
}

// ---------------------------------------------------------------------------
// f16 MFMA GEMM, 64 x BN tile, BK-chunk K-loop. Block 256 thr = 4 waves;
// wave-tile 32 x (BN/2), MI=2 m-frags. BK in {32,64}.
// Modes: 0 plain / 1 in_proj fused (REQUIRES BK=64, BN=128; Tz aliases Ws) /
// 2 xproj split / 3 dtproj transposed-softplus.
// MFMA layouts (m89/m120-verified): A-frag A[m=lane&15][k=q*8+j],
// B-frag B[k=q*8+j][n=lane&15], D: col(n)=lane&15, row(m)=q*4+r.
// ---------------------------------------------------------------------------
template<int BN, int BK, int ACT, int OF16, int MODE>
__global__ __launch_bounds__(256)
void gemm_mfma(const _Float16* __restrict__ A, int lda,
               const _Float16* __restrict__ W,
               const float* __restrict__ bias,
               void* __restrict__ Cv, int ldc,
               int N, int K, float oscale,
               void* __restrict__ Cv2)
{
  static_assert(MODE != 1 || (BK == 64 && BN == 128), "MODE1 needs BK=64/BN=128");
  constexpr int NF  = BN / 32;           // n-frags per wave
  constexpr int LS  = BK + 8;            // LDS row stride in halfs (16B-aligned)
  constexpr int NA  = BK / 32;           // A half8 regs per thread
  constexpr int WTR = 256 / BN;          // threads per W row
  constexpr int WH  = BK / WTR;          // W halfs per thread (R18b fix)
  constexpr int NW  = WH / 8;            // W half8 regs per thread
  static_assert(NA >= 1 && NW >= 1, "staging arithmetic");

  __shared__ _Float16 As[64 * LS];
  __shared__ _Float16 Ws[BN * LS];       // MODE1: reused as Tz in epilogue
  __shared__ float    Td[(MODE == 3) ? 64 * 68 : 2];
  const int tid  = threadIdx.x;
  const int lane = tid & 63;
  const int wid  = tid >> 6;
  const int wm   = wid & 1, wn = wid >> 1;   // wave-tile: 32 m x BN/2 n
  const int m0   = blockIdx.y * 64;
  const int n0   = blockIdx.x * BN;
  const int q    = lane >> 4, l16 = lane & 15;

  // staging coords
  const int ar  = tid >> 2;                  // A: 4 thr/row
  const int akq = (tid & 3) * (BK / 4);
  const int wr  = tid / WTR;
  const int wkq = (tid % WTR) * WH;
  const int wrow = n0 + wr;
  const bool wv  = (wrow < N);

  const _Float16* Wp = W + (size_t)wrow * K;
  const size_t aoff = (size_t)(m0 + ar) * lda + akq;

  half8 zh;
  #pragma unroll
  for (int i = 0; i < 8; ++i) zh[i] = (_Float16)0.f;

  // initial loads (k0 = 0)
  half8 rah[NA], rwh[NW];
  #pragma unroll
  for (int i = 0; i < NA; ++i) rah[i] = *(const half8*)(A + aoff + i * 8);
  #pragma unroll
  for (int j = 0; j < NW; ++j)
    rwh[j] = wv ? *(const half8*)(Wp + wkq + j * 8) : zh;

  f32x4 acc[2][NF];
  #pragma unroll
  for (int mi = 0; mi < 2; ++mi)
    #pragma unroll
    for (int ni = 0; ni < NF; ++ni)
      acc[mi][ni] = (f32x4){0.f, 0.f, 0.f, 0.f};

  for (int k0 = 0; k0 < K; k0 += BK) {
    if (k0) __syncthreads();
    #pragma unroll
    for (int i = 0; i < NA; ++i)
      *(half8*)&As[ar * LS + akq + i * 8] = rah[i];
    #pragma unroll
    for (int j = 0; j < NW; ++j)
      *(half8*)&Ws[wr * LS + wkq + j * 8] = rwh[j];
    __syncthreads();

    if (k0 + BK < K) {            // prefetch next chunk
      const int kn = k0 + BK;
      #pragma unroll
      for (int i = 0; i < NA; ++i)
        rah[i] = *(const half8*)(A + aoff + kn + i * 8);
      if (wv) {
        #pragma unroll
        for (int j = 0; j < NW; ++j)
          rwh[j] = *(const half8*)(Wp + kn + wkq + j * 8);
      }
    }

    #pragma unroll
    for (int kk = 0; kk < BK / 32; ++kk) {
      half8 af[2], wf[NF];
      #pragma unroll
      for (int mi = 0; mi < 2; ++mi)
        af[mi] = *(const half8*)&As[(wm * 32 + mi * 16 + l16) * LS + kk * 32 + q * 8];
      #pragma unroll
      for (int ni = 0; ni < NF; ++ni)
        wf[ni] = *(const half8*)&Ws[(wn * (BN / 2) + ni * 16 + l16) * LS + kk * 32 + q * 8];
      #pragma unroll
      for (int mi = 0; mi < 2; ++mi)
        #pragma unroll
        for (int ni = 0; ni < NF; ++ni)
          acc[mi][ni] = __builtin_amdgcn_mfma_f32_16x16x32_f16(af[mi], wf[ni],
                                                               acc[mi][ni], 0, 0, 0);
    }
  }

  float*    Cf = (float*)Cv;
  _Float16* Ch = (_Float16*)Cv;

  if (MODE == 1) {
    if (n0 < 1024) {
      // xc half: f16 [M][1024]
      #pragma unroll
      for (int ni = 0; ni < NF; ++ni) {
        const int n = n0 + wn * (BN / 2) + ni * 16 + l16;
        #pragma unroll
        for (int mi = 0; mi < 2; ++mi) {
          const int mb = m0 + wm * 32 + mi * 16 + q * 4;
          #pragma unroll
          for (int r = 0; r < 4; ++r)
            Ch[(size_t)(mb + r) * 1024 + n] = (_Float16)(acc[mi][ni][r] * oscale);
        }
      }
    } else {
      // z half: silu -> f16, LDS transpose (Tz aliases Ws; LS==72),
      // coalesced 16B row stores
      _Float16* Tz = Ws;
      _Float16* Ch2 = (_Float16*)Cv2;
      __syncthreads();                  // all MFMA reads of Ws done
      #pragma unroll
      for (int ni = 0; ni < NF; ++ni) {
        const int nnl = wn * (BN / 2) + ni * 16 + l16;   // 0..127 local
        #pragma unroll
        for (int mi = 0; mi < 2; ++mi) {
          const int mbl = wm * 32 + mi * 16 + q * 4;     // 0..63 local
          half4v h4;
          #pragma unroll
          for (int r = 0; r < 4; ++r)
            h4[r] = (_Float16)silu_f(acc[mi][ni][r] * oscale);
          *(half4v*)&Tz[nnl * LS + mbl] = h4;
        }
      }
      __syncthreads();
      const int sr = tid >> 3;          // 0..31
      const int sc = (tid & 7) * 8;     // halfs 0..56
      #pragma unroll
      for (int rd = 0; rd < 4; ++rd) {
        const int row = rd * 32 + sr;
        half8 v = *(const half8*)&Tz[row * LS + sc];
        *(half8*)&Ch2[(size_t)(n0 - 1024 + row) * 4096 + m0 + sc] = v;
      }
    }
    return;
  }

  if (MODE == 2) {
    // xproj: n<32 -> dtr16 f16 [M][32]; 32<=n<160 -> dbc fp32 [M][160]
    _Float16* dtr = (_Float16*)Cv2;
    #pragma unroll
    for (int ni = 0; ni < NF; ++ni) {
      const int n = n0 + wn * (BN / 2) + ni * 16 + l16;
      #pragma unroll
      for (int mi = 0; mi < 2; ++mi) {
        const int mb = m0 + wm * 32 + mi * 16 + q * 4;
        if (n < 32) {
          #pragma unroll
          for (int r = 0; r < 4; ++r)
            dtr[(size_t)(mb + r) * 32 + n] = (_Float16)acc[mi][ni][r];
        } else if (n < 160) {
          #pragma unroll
          for (int r = 0; r < 4; ++r)
            Cf[(size_t)(mb + r) * 160 + n] = acc[mi][ni][r];
        }
      }
    }
    return;
  }

  if (MODE == 3) {
    // dtproj: softplus(acc*oscale + bias) -> fp32 [N][4096] via LDS transpose
    __syncthreads();
    #pragma unroll
    for (int ni = 0; ni < NF; ++ni) {
      const int nnl = wn * (BN / 2) + ni * 16 + l16;     // 0..63 local
      const float bv = (bias != nullptr) ? bias[n0 + nnl] : 0.f;
      #pragma unroll
      for (int mi = 0; mi < 2; ++mi) {
        const int mbl = wm * 32 + mi * 16 + q * 4;       // 0..63 local
        float o[4];
        #pragma unroll
        for (int r = 0; r < 4; ++r) {
          float v = acc[mi][ni][r] * oscale + bv;
          o[r] = (v > 20.f) ? v : log1pf(__expf(v));     // softplus
        }
        *(float4*)&Td[nnl * 68 + mbl] = make_float4(o[0], o[1], o[2], o[3]);
      }
    }
    __syncthreads();
    const int sr = tid >> 4;            // 0..15
    const int sc = (tid & 15) * 4;      // floats 0..60
    #pragma unroll
    for (int rd = 0; rd < 4; ++rd) {
      const int row = rd * 16 + sr;
      float4 v = *(const float4*)&Td[row * 68 + sc];
      *(float4*)&Cf[(size_t)(n0 + row) * 4096 + m0 + sc] = v;
    }
    return;
  }

  // MODE 0 epilogue
  #pragma unroll
  for (int ni = 0; ni < NF; ++ni) {
    const int n = n0 + wn * (BN / 2) + ni * 16 + l16;
    if (n < N) {
      const float bv = (bias != nullptr) ? bias[n] : 0.f;
      #pragma unroll
      for (int mi = 0; mi < 2; ++mi) {
        const int mb = m0 + wm * 32 + mi * 16 + q * 4;
        #pragma unroll
        for (int r = 0; r < 4; ++r) {
          float v = acc[mi][ni][r] * oscale + bv;
          if (ACT == 1) v = (v > 20.f) ? v : log1pf(__expf(v));
          if (ACT == 2) v = silu_f(v);
          size_t off = (size_t)(mb + r) * ldc + n;
          if (OF16) Ch[off] = (_Float16)v;
          else      Cf[off] = v;
        }
      }
    }
  }
}

// ---------------------------------------------------------------------------
// Depthwise causal conv (D_CONV=2) + silu, 64x64 LDS transpose.
// in : xcp [4096 bl][1024 d] f16
// out: xcT [1024 d][4096 bl] fp32 (scan input)  +  xcf [4096 bl][1024 d] f16
// ---------------------------------------------------------------------------
__global__ void conv_t_kernel(const _Float16* __restrict__ xcp,
                              const float* __restrict__ cw,   // [1024][2]
                              const float* __restrict__ cb,   // [1024]
                              float* __restrict__ xcT,
                              _Float16* __restrict__ xcf)
{
  __shared__ float tile[64][65];
  const int blk = blockIdx.x;            // b*256 + tt*16 + dd
  const int b  = blk >> 8;
  const int tt = (blk >> 4) & 15;
  const int dd = blk & 15;
  const int t0 = tt * 64, d0 = dd * 64;
  const int tid = threadIdx.x;

  #pragma unroll
  for (int i = 0; i < 16; ++i) {
    int idx = i * 256 + tid;
    int t = idx >> 6, d = idx & 63;
    int gt = t0 + t;
    size_t rcur = ((size_t)(b * 1024 + gt) << 10) + d0 + d;
    float cur  = (float)xcp[rcur];
    float prev = (gt > 0) ? (float)xcp[rcur - 1024] : 0.f;
    float v = fmaf(prev, cw[(d0+d)*2], fmaf(cur, cw[(d0+d)*2 + 1], cb[d0+d]));
    float sv = silu_f(v);
    tile[t][d] = sv;
    xcf[rcur] = (_Float16)sv;
  }
  __syncthreads();
  #pragma unroll
  for (int i = 0; i < 16; ++i) {
    int idx = i * 256 + tid;
    int d = idx >> 6, t = idx & 63;
    xcT[((size_t)(d0 + d) << 12) + b * 1024 + t0 + t] = tile[t][d];
  }
}

// ---------------------------------------------------------------------------
// Selective scan, time-major. One wave per (b,d), lane = s (D_STATE=64).
// R17-proven: barrier-free; B/C direct from global, per-lane coalesced;
// wave-private P tile; XCD swizzle; direct f16 y store (x 2^14 exact).
// ---------------------------------------------------------------------------
__global__ __launch_bounds__(256, 4)
void scan_kernel(const float* __restrict__ dtT,     // [1024][4096]
                 const float* __restrict__ xcT,     // [1024][4096]
                 const _Float16* __restrict__ zsT,  // [1024][4096], silu(z), f16
                 const float* __restrict__ dbc,     // [B][1024][160]; B@+32, C@+96
                 const float* __restrict__ A_log,   // [1024][64]
                 const float* __restrict__ Dp,      // [1024]
                 _Float16* __restrict__ y16)        // [4096 bl][1024 d], y*2^14
{
  __shared__ float P[4][16][68];       // per-wave reduction tile (wave-private)
  const int tid  = threadIdx.x;
  const int lane = tid & 63;
  const int wrp  = tid >> 6;
  const int rb   = blockIdx.x;
  const int bswz = ((rb & 7) << 7) | (rb >> 3);          // XCD swizzle
  const int wid  = __builtin_amdgcn_readfirstlane(bswz * 4 + wrp);
  const int b = wid >> 10;
  const int d = wid & 1023;
  float (*Pw)[68] = P[wrp];

  const float a   = -__expf(A_log[d*64 + lane]);
  const float dpv = Dp[d];
  const size_t row = ((size_t)d << 12) + b * 1024;
  const float*    dtp = dtT + row;
  const float*    xp  = xcT + row;
  const _Float16* zsp = zsT + row;
  _Float16*       yp  = y16 + ((size_t)b << 20) + d;     // + t*1024
  const float*    bcp = dbc + (size_t)b * 163840 + lane; // + t*160 (+32/+96)

  const int tt_r = lane >> 2;
  const int c0   = (lane & 3) << 4;

  float h = 0.f;
  for (int t0 = 0; t0 < 1024; t0 += 16) {
    // ---- chunk loads: all independent, issue together ----
    const float* bp = bcp + (size_t)t0 * 160;
    float Bv[16], Cv[16];
    #pragma unroll
    for (int tt = 0; tt < 16; ++tt) {
      Bv[tt] = bp[tt * 160 + 32];     // coalesced 64-lane run
      Cv[tt] = bp[tt * 160 + 96];
    }
    float4 dq[4], xq[4];
    #pragma unroll
    for (int i = 0; i < 4; ++i) {
      dq[i] = *(const float4*)(dtp + t0 + i*4);
      xq[i] = *(const float4*)(xp  + t0 + i*4);
    }
    float zs  = (float)zsp[t0 + tt_r] * Y_SCALE;   // exact 2^14 fold
    float xvl = xp[t0 + tt_r];
    const float* dtv = reinterpret_cast<const float*>(dq);
    const float* xv  = reinterpret_cast<const float*>(xq);

    // ---- parallel phase: everything h-independent ----
    float dA[16], ub[16];
    #pragma unroll
    for (int tt = 0; tt < 16; ++tt) {
      dA[tt] = __expf(dtv[tt] * a);
      ub[tt] = dtv[tt] * xv[tt] * Bv[tt];
    }
    // ---- serial recurrence: fma -> mul -> ds_write per t ----
    #pragma unroll
    for (int tt = 0; tt < 16; ++tt) {
      h = fmaf(h, dA[tt], ub[tt]);
      Pw[tt][lane] = h * Cv[tt];
    }

    // ---- batched reduction: lane L sums 16 states of timestep L>>2 ----
    float4 s0 = *(const float4*)&Pw[tt_r][c0];
    float4 s1 = *(const float4*)&Pw[tt_r][c0 + 4];
    float4 s2 = *(const float4*)&Pw[tt_r][c0 + 8];
    float4 s3 = *(const float4*)&Pw[tt_r][c0 + 12];
    float r = ((s0.x + s0.y) + (s0.z + s0.w))
            + ((s1.x + s1.y) + (s1.z + s1.w))
            + ((s2.x + s2.y) + (s2.z + s2.w))
            + ((s3.x + s3.y) + (s3.z + s3.w));
    r += __shfl_xor(r, 1, 64);
    r += __shfl_xor(r, 2, 64);
    if ((lane & 3) == 0)
      yp[(size_t)(t0 + tt_r) << 10] = (_Float16)(fmaf(xvl, dpv, r) * zs);
    // no __syncthreads: P is wave-private, ordered by lgkmcnt.
  }
}

// ---------------------------------------------------------------------------
// Fused out_proj(l1)+fc head: only h[b, L-1, :] reaches the output.
// out[b,c] = (sum_di y16l1[b*1024+1023][di] * w2[c][di]) * 2^-14 + fc_b[c],
// w2[c][di] = sum_dm fc_w[c][dm] * out_w1[dm][di]   (fp32 weights).
// ---------------------------------------------------------------------------
__global__ void head2_kernel(const _Float16* __restrict__ y16,
                             const float* __restrict__ out_w1,  // [512][1024]
                             const float* __restrict__ fc_w,    // [3][512]
                             const float* __restrict__ fc_b,
                             float* __restrict__ out)
{
  __shared__ float red[4];
  const int bc = blockIdx.x;            // 0..11
  const int b = bc / 3, c = bc % 3;
  const int tid = threadIdx.x;
  const int lane = tid & 63, wv = tid >> 6;

  float4 w2 = make_float4(0.f, 0.f, 0.f, 0.f);
  const float* fcr = fc_w + c * 512;
  const float* owp = out_w1 + tid * 4;
  for (int dm = 0; dm < 512; ++dm) {
    float f = fcr[dm];
    float4 o = *(const float4*)(owp + (size_t)dm * 1024);
    w2.x = fmaf(f, o.x, w2.x); w2.y = fmaf(f, o.y, w2.y);
    w2.z = fmaf(f, o.z, w2.z); w2.w = fmaf(f, o.w, w2.w);
  }
  const _Float16* yr = y16 + ((size_t)(b * 1024 + 1023) << 10) + tid * 4;
  half4v yv = *(const half4v*)yr;
  float s = (float)yv[0] * w2.x + (float)yv[1] * w2.y
          + (float)yv[2] * w2.z + (float)yv[3] * w2.w;
  #pragma unroll
  for (int o = 32; o > 0; o >>= 1) s += __shfl_xor(s, o, 64);
  if (lane == 0) red[wv] = s;
  __syncthreads();
  if (tid == 0)
    out[b * 3 + c] = (red[0] + red[1] + red[2] + red[3]) * (1.f / Y_SCALE)
                     + fc_b[c];
}

extern "C" void kernel_launch(void* const* d_in, const int* in_sizes, int n_in,
                              void* d_out, int out_size, void* d_ws, size_t ws_size,
                              hipStream_t stream)
{
  const float* x        = (const float*)d_in[0];
  const float* exp_w    = (const float*)d_in[1];
  const float* exp_b    = (const float*)d_in[2];
  const float* in_w     = (const float*)d_in[3];
  const float* conv_w   = (const float*)d_in[4];
  const float* conv_b   = (const float*)d_in[5];
  const float* xproj_w  = (const float*)d_in[6];
  const float* dtproj_w = (const float*)d_in[7];
  const float* dtproj_b = (const float*)d_in[8];
  const float* A_log    = (const float*)d_in[9];
  const float* Dp       = (const float*)d_in[10];
  const float* out_w    = (const float*)d_in[11];
  const float* fc_w     = (const float*)d_in[12];
  const float* fc_b     = (const float*)d_in[13];
  float* out = (float*)d_out;

  // Workspace layout (byte offsets), 72 MB total.
  // 4..20 MB region sequentially reused: xcpre16 (8MB) -> dtT (16MB).
  char* ws = (char*)d_ws;
  _Float16* hf16    = (_Float16*)(ws);                        //  4 MB [4096][512] f16
  _Float16* xcpre16 = (_Float16*)(ws + ((size_t)4  << 20));   //  8 MB [4096][1024] f16
  float*    dtT     = (float*)   (ws + ((size_t)4  << 20));   // 16 MB [1024][4096] (reuse)
  float*    xcT     = (float*)   (ws + ((size_t)20 << 20));   // 16 MB [1024][4096]
  _Float16* zsT     = (_Float16*)(ws + ((size_t)36 << 20));   //  8 MB [1024][4096]
  float*    dbc     = (float*)   (ws + ((size_t)44 << 20));   //  2.6 MB [4096][160]
  _Float16* dtr16   = (_Float16*)(ws + ((size_t)47 << 20));   //  0.25 MB [4096][32]
  _Float16* xc16    = (_Float16*)(ws + ((size_t)48 << 20));   //  8 MB [4096][1024]
  _Float16* y16     = (_Float16*)(ws + ((size_t)56 << 20));   //  8 MB [4096][1024]
  _Float16* w16     = (_Float16*)(ws + ((size_t)64 << 20));   //  7.9 MB f16 pool

  _Float16* exp16 = w16;                 // [512][128]
  _Float16* in16  = w16 + 65536;         // [2][2048][512]
  _Float16* xp16  = w16 + 2162688;       // [2][160][1024]
  _Float16* dt16  = w16 + 2490368;       // [2][1024][32]
  _Float16* out16 = w16 + 2555904;       // [2][512][1024]
  _Float16* x16   = w16 + 3604480;       // [4096][128]

  dim3 blk(256);

  // one-shot f16 conversion of all weights + x (4128768 elems, 4032 blocks)
  wcvt_kernel<<<4032, blk, 0, stream>>>(exp_w, in_w, xproj_w, dtproj_w, out_w,
                                        x, w16);

  // expand: hf16 = f16(x @ exp_w^T + exp_b)   [4096,512] K=128, BK=32.
  gemm_mfma<64,32,0,1,0><<<dim3(8,64), blk, 0, stream>>>(x16, 128, exp16, exp_b,
                                                         hf16, 512, 512, 128, 1.f,
                                                         nullptr);

  for (int l = 0; l < 2; ++l) {
    const float is = l ? (1.f / H1_SCALE) : 1.f;     // undo h1 scaling (exact)
    // fused in_proj: xcpre16 f16 + zsT f16 (Tz aliases Ws). N=2048 K=512 BK=64.
    gemm_mfma<128,64,0,0,1><<<dim3(16,64), blk, 0, stream>>>(hf16, 512,
                                                             in16 + (size_t)l*1048576,
                                                             nullptr, xcpre16, 1024,
                                                             2048, 512, is, zsT);
    // conv + silu -> xcT (fp32, scan) + xc16 (f16, xproj A)
    conv_t_kernel<<<1024, blk, 0, stream>>>(xcpre16, conv_w + l*2048, conv_b + l*1024,
                                            xcT, xc16);
    // xproj (MODE 2): dtr16 f16 [4096][32] + dbc fp32 [4096][160]. K=1024 BK=64.
    gemm_mfma<64,64,0,0,2><<<dim3(3,64), blk, 0, stream>>>(xc16, 1024,
                                                           xp16 + (size_t)l*163840,
                                                           nullptr, dbc, 160,
                                                           160, 1024, 1.f, dtr16);
    // dtproj (MODE 3): dtT [1024][4096] softplus, LDS-transposed. K=32 BK=32.
    gemm_mfma<64,32,0,0,3><<<dim3(16,64), blk, 0, stream>>>(dtr16, 32,
                                                            dt16 + (size_t)l*32768,
                                                            dtproj_b + l*1024,
                                                            dtT, 4096, 1024, 32, 1.f,
                                                            nullptr);
    // selective scan (barrier-free); y16 = f16((scan + x*Dp)*silu(z) * 2^14)
    scan_kernel<<<1024, blk, 0, stream>>>(dtT, xcT, zsT, dbc,
                                          A_log + (size_t)l*65536, Dp + l*1024, y16);
    // out_proj only for layer 0 (layer-1 h only matters at t=L-1 -> head2)
    if (l == 0)
      gemm_mfma<64,64,0,1,0><<<dim3(8,64), blk, 0, stream>>>(y16, 1024,
                                                             out16, nullptr,
                                                             hf16, 512, 512, 1024,
                                                             H1_SCALE / Y_SCALE,
                                                             nullptr);
  }

  // fused out_proj(l1) + fc head from y16(l1) directly (fp32 weights)
  head2_kernel<<<12, blk, 0, stream>>>(y16, out_w + (size_t)512*1024,
                                       fc_w, fc_b, out);
}